// Round 7
// baseline (43694.867 us; speedup 1.0000x reference)
//
#include <hip/hip_runtime.h>
#include <stdint.h>
#include <math.h>

namespace {

constexpr int B = 256, L = 256, F = 38, H = 512, D = 512, Z = 16, NF = 20;
constexpr float LOG2PI_F = 1.8378770664093453f;
constexpr int LBZ = L * B * Z;      // 1048576
constexpr int HALF = LBZ / 2;       // 524288
constexpr int HB = H * B;           // 131072
constexpr int DB = D * B;           // 131072
constexpr int ZB = Z * B;           // 4096
constexpr int LFB = L * F * B;      // 2490368
constexpr int GRIDN = 512;          // persistent grid: 2 blocks/CU on 256 CUs

// ---------------- coherent activation access (cross-XCD via L3) ------------
// sc1 path (SLOW fallback): agent-scope relaxed atomics bypass per-XCD L2.
__device__ __forceinline__ float aload_(const float* p) {
  return __hip_atomic_load(p, __ATOMIC_RELAXED, __HIP_MEMORY_SCOPE_AGENT);
}
__device__ __forceinline__ void astore_(float* p, float v) {
  __hip_atomic_store(p, v, __ATOMIC_RELAXED, __HIP_MEMORY_SCOPE_AGENT);
}

// ---------------- math helpers ----------------

__device__ __forceinline__ float sigmoidf_(float x) {
  return 1.0f / (1.0f + expf(-x));
}
__device__ __forceinline__ float softplusf_(float x) {
  return fmaxf(x, 0.0f) + log1pf(expf(-fabsf(x)));
}

__device__ __forceinline__ void waveReduceAtomicAdd(float* dst, float v, int tid) {
  #pragma unroll
  for (int off = 32; off > 0; off >>= 1) v += __shfl_down(v, off, 64);
  if ((tid & 63) == 0) atomicAdd(dst, v);
}

// ---------------- 3-level grid barrier (monotone, RELAXED-only) ------------
// Proven R6. Cross-block data is published either via sc1 (slow path) or via
// same-XCD L2 (fast path); __syncthreads at entry drains each thread's
// stores (compiler emits vmcnt(0) before s_barrier), so relaxed RMWs suffice.
__device__ __forceinline__ void gsync_(uint32_t* bar, int blk, uint32_t n) {
  __syncthreads();
  if (threadIdx.x == 0) {
    asm volatile("s_waitcnt vmcnt(0)" ::: "memory");
    const uint32_t tgt = 8u * n - 1u;
    uint32_t o1 = __hip_atomic_fetch_add(&bar[192 + ((blk >> 3) << 4)], 1u,
                                         __ATOMIC_RELAXED, __HIP_MEMORY_SCOPE_AGENT);
    if (o1 == tgt) {
      uint32_t o2 = __hip_atomic_fetch_add(&bar[32 + ((blk >> 6) << 4)], 1u,
                                           __ATOMIC_RELAXED, __HIP_MEMORY_SCOPE_AGENT);
      if (o2 == tgt) {
        uint32_t o3 = __hip_atomic_fetch_add(&bar[16], 1u,
                                             __ATOMIC_RELAXED, __HIP_MEMORY_SCOPE_AGENT);
        if (o3 == tgt)
          __hip_atomic_store(&bar[0], n, __ATOMIC_RELAXED, __HIP_MEMORY_SCOPE_AGENT);
      }
    }
    while (__hip_atomic_load(&bar[0], __ATOMIC_RELAXED, __HIP_MEMORY_SCOPE_AGENT) < n)
      __builtin_amdgcn_s_sleep(1);
  }
  __syncthreads();
}

// Invalidate vector L1 so plain loads observe the local XCD L2 (fast path).
// `buffer_inv sc1` is the exact sequence hipcc emits for agent-acquire.
__device__ __forceinline__ void l1inv_() {
  asm volatile("buffer_inv sc1" ::: "memory");
}

// ---------------- threefry2x32 (JAX-compatible) ----------------

__host__ __device__ inline uint32_t rotl32_(uint32_t x, int d) {
  return (x << d) | (x >> (32 - d));
}

__host__ __device__ inline void threefry2x32_(uint32_t k0, uint32_t k1,
                                              uint32_t x0, uint32_t x1,
                                              uint32_t& o0, uint32_t& o1) {
  const uint32_t ks2 = k0 ^ k1 ^ 0x1BD11BDAu;
  uint32_t v0 = x0 + k0;
  uint32_t v1 = x1 + k1;
#define TF_RND(r) { v0 += v1; v1 = rotl32_(v1, r); v1 ^= v0; }
  TF_RND(13) TF_RND(15) TF_RND(26) TF_RND(6)
  v0 += k1;  v1 += ks2 + 1u;
  TF_RND(17) TF_RND(29) TF_RND(16) TF_RND(24)
  v0 += ks2; v1 += k0 + 2u;
  TF_RND(13) TF_RND(15) TF_RND(26) TF_RND(6)
  v0 += k0;  v1 += k1 + 3u;
  TF_RND(17) TF_RND(29) TF_RND(16) TF_RND(24)
  v0 += k1;  v1 += ks2 + 4u;
  TF_RND(13) TF_RND(15) TF_RND(26) TF_RND(6)
  v0 += ks2; v1 += k0 + 5u;
#undef TF_RND
  o0 = v0; o1 = v1;
}

__device__ __forceinline__ float erfinv_f_(float x) {
  float w = -log1pf(-x * x);
  float p;
  if (w < 5.0f) {
    w -= 2.5f;
    p = 2.81022636e-08f;
    p = fmaf(p, w, 3.43273939e-07f);
    p = fmaf(p, w, -3.5233877e-06f);
    p = fmaf(p, w, -4.39150654e-06f);
    p = fmaf(p, w, 0.00021858087f);
    p = fmaf(p, w, -0.00125372503f);
    p = fmaf(p, w, -0.00417768164f);
    p = fmaf(p, w, 0.246640727f);
    p = fmaf(p, w, 1.50140941f);
  } else {
    w = sqrtf(w) - 3.0f;
    p = -0.000200214257f;
    p = fmaf(p, w, 0.000100950558f);
    p = fmaf(p, w, 0.00134934322f);
    p = fmaf(p, w, -0.00367342844f);
    p = fmaf(p, w, 0.00573950773f);
    p = fmaf(p, w, -0.0076224613f);
    p = fmaf(p, w, 0.00943887047f);
    p = fmaf(p, w, 1.00167406f);
    p = fmaf(p, w, 2.83297682f);
  }
  return p * x;
}

__device__ __forceinline__ float bits_to_normal_(uint32_t bits) {
  uint32_t m = (bits >> 9) | 0x3f800000u;
  float f = __uint_as_float(m) - 1.0f;
  float u = f * 2.0f + (-0.99999994f);
  u = fmaxf(-0.99999994f, u);
  return 1.41421356f * erfinv_f_(u);
}

// planar flows for one batch column (per-lane), returns logdet; zv updated in place
__device__ __forceinline__ float flows_dev(float zv[Z], const float* __restrict__ pu,
                                           const float* __restrict__ pw,
                                           const float* __restrict__ pb) {
  float ld = 0.0f;
  for (int f = 0; f < NF; ++f) {
    const float* w = pw + f * Z;
    const float* u = pu + f * Z;
    float wn2 = 0.0f, wu = 0.0f;
    #pragma unroll
    for (int i = 0; i < Z; ++i) { wn2 = fmaf(w[i], w[i], wn2); wu = fmaf(w[i], u[i], wu); }
    float coef = (softplusf_(wu) - 1.0f - wu) / wn2;
    float a_in = pb[f];
    #pragma unroll
    for (int i = 0; i < Z; ++i) a_in = fmaf(zv[i], w[i], a_in);
    float a = tanhf(a_in);
    float uw = 0.0f;
    #pragma unroll
    for (int i = 0; i < Z; ++i) {
      float uh = fmaf(coef, w[i], u[i]);
      uw = fmaf(uh, w[i], uw);
      zv[i] = fmaf(uh, a, zv[i]);
    }
    ld += logf(fabsf(1.0f + (1.0f - a * a) * uw) + 1e-12f);
  }
  return ld;
}

// ---------------- small utility kernels ----------------

__global__ __launch_bounds__(256) void k_transpose_x(const float* __restrict__ x,
                                                     float* __restrict__ xT) {
  int idx = blockIdx.x * blockDim.x + threadIdx.x;  // over B*L*F
  int f = idx % F;
  int t = (idx / F) % L;
  int b = idx / (F * L);
  xT[(t * F + f) * B + b] = x[idx];
}

__global__ __launch_bounds__(256) void k_noise(float* __restrict__ eps_z,
                                               float* __restrict__ kld_acc,
                                               uint32_t kz0, uint32_t kz1,
                                               uint32_t kp0, uint32_t kp1) {
  int i = blockIdx.x * blockDim.x + threadIdx.x;  // [0, HALF)
  uint32_t a0, a1, b0, b1;
  threefry2x32_(kz0, kz1, (uint32_t)i, (uint32_t)(i + HALF), a0, a1);
  float ez0 = bits_to_normal_(a0);
  float ez1 = bits_to_normal_(a1);
  eps_z[i] = ez0;
  eps_z[i + HALF] = ez1;
  threefry2x32_(kp0, kp1, (uint32_t)i, (uint32_t)(i + HALF), b0, b1);
  float ep0 = bits_to_normal_(b0);
  float ep1 = bits_to_normal_(b1);
  float local = -0.5f * (ez0 * ez0 + ez1 * ez1) + 0.5f * (ep0 * ep0 + ep1 * ep1);
  waveReduceAtomicAdd(kld_acc, local, threadIdx.x);
}

__global__ void k_finalize(const float* __restrict__ acc, float* __restrict__ out) {
  out[(size_t)B * L * F] = acc[1];      // recon
  out[(size_t)B * L * F + 1] = acc[0];  // kld
}

// ---------------- weight composition (once per launch) ----------------
__global__ __launch_bounds__(256) void k_compose(
    const float* __restrict__ A, const float* __restrict__ bA,
    const float* __restrict__ W2, const float* __restrict__ b2,
    float* __restrict__ Wc, float* __restrict__ bc) {
  const int r = blockIdx.x;
  const int k = threadIdx.x;
  float acc0 = 0.f, acc1 = 0.f;
  for (int j = 0; j < D; ++j) {
    float a = A[(size_t)r * D + j];          // wave-uniform
    acc0 = fmaf(a, W2[(size_t)j * D + k], acc0);
    acc1 = fmaf(a, W2[(size_t)j * D + k + 256], acc1);
  }
  Wc[(size_t)r * D + k] = acc0;
  Wc[(size_t)r * D + k + 256] = acc1;
  float accb = 0.f;
  for (int j = k; j < D; j += 256) accb += A[(size_t)r * D + j] * b2[j];
  __shared__ float s[256];
  s[k] = accb;
  __syncthreads();
  for (int off = 128; off > 0; off >>= 1) {
    if (k < off) s[k] += s[k + off];
    __syncthreads();
  }
  if (k == 0) bc[r] = s[0] + bA[r];
}

// ====================== FAST PATH (XCD-local, plain L2) =====================
// 8 batch-groups (bg) x 32 cols; bg == physical XCD (verified at runtime).
// Thread layout: col = tid&31, q = tid>>5 in [0,8). Full-K dots per thread,
// no LDS reduction. All activation traffic stays inside one XCD's L2.

// GRU: 256 blocks; rb = blk2>>3 (16 rows), bg = blk2&7. 2 rows/thread.
template<bool THETA>
__device__ __forceinline__ void gruF_(
    int blk2, const float* __restrict__ xin, const float* __restrict__ hT,
    const float* __restrict__ Wih, const float* __restrict__ Whh,
    const float* __restrict__ bih, const float* __restrict__ bhh,
    float* __restrict__ hout) {
  const int t = threadIdx.x;
  const int col = t & 31;
  const int q = t >> 5;
  const int bg = blk2 & 7;
  const int b = bg * 32 + col;
  const int j0 = (blk2 >> 3) * 16 + q * 2;
  constexpr int K1 = THETA ? Z : F;

  float r0 = 0.f, r1 = 0.f, z0 = 0.f, z1 = 0.f;
  float nx0 = 0.f, nx1 = 0.f, nh0 = 0.f, nh1 = 0.f;

  {  // x/z part
    const float* wr = Wih + (size_t)(0 * H + j0) * K1;
    const float* wz = Wih + (size_t)(1 * H + j0) * K1;
    const float* wn = Wih + (size_t)(2 * H + j0) * K1;
    #pragma unroll 2
    for (int k = 0; k < K1; ++k) {
      const float a = xin[(size_t)k * B + b];
      r0  = fmaf(wr[k], a, r0);        r1  = fmaf(wr[K1 + k], a, r1);
      z0  = fmaf(wz[k], a, z0);        z1  = fmaf(wz[K1 + k], a, z1);
      nx0 = fmaf(wn[k], a, nx0);       nx1 = fmaf(wn[K1 + k], a, nx1);
    }
  }
  {  // h part
    const float* vr = Whh + (size_t)(0 * H + j0) * H;
    const float* vz = Whh + (size_t)(1 * H + j0) * H;
    const float* vn = Whh + (size_t)(2 * H + j0) * H;
    #pragma unroll 2
    for (int k = 0; k < H; k += 4) {
      const float a0 = hT[(size_t)(k + 0) * B + b];
      const float a1 = hT[(size_t)(k + 1) * B + b];
      const float a2 = hT[(size_t)(k + 2) * B + b];
      const float a3 = hT[(size_t)(k + 3) * B + b];
      const float4 wr0 = *(const float4*)(vr + k);
      const float4 wr1 = *(const float4*)(vr + H + k);
      const float4 wz0 = *(const float4*)(vz + k);
      const float4 wz1 = *(const float4*)(vz + H + k);
      const float4 wn0 = *(const float4*)(vn + k);
      const float4 wn1 = *(const float4*)(vn + H + k);
      r0  = fmaf(wr0.x, a0, fmaf(wr0.y, a1, fmaf(wr0.z, a2, fmaf(wr0.w, a3, r0))));
      r1  = fmaf(wr1.x, a0, fmaf(wr1.y, a1, fmaf(wr1.z, a2, fmaf(wr1.w, a3, r1))));
      z0  = fmaf(wz0.x, a0, fmaf(wz0.y, a1, fmaf(wz0.z, a2, fmaf(wz0.w, a3, z0))));
      z1  = fmaf(wz1.x, a0, fmaf(wz1.y, a1, fmaf(wz1.z, a2, fmaf(wz1.w, a3, z1))));
      nh0 = fmaf(wn0.x, a0, fmaf(wn0.y, a1, fmaf(wn0.z, a2, fmaf(wn0.w, a3, nh0))));
      nh1 = fmaf(wn1.x, a0, fmaf(wn1.y, a1, fmaf(wn1.z, a2, fmaf(wn1.w, a3, nh1))));
    }
  }
  const int j1 = j0 + 1;
  const float rg0 = sigmoidf_(r0 + bih[j0] + bhh[j0]);
  const float rg1 = sigmoidf_(r1 + bih[j1] + bhh[j1]);
  const float zg0 = sigmoidf_(z0 + bih[H + j0] + bhh[H + j0]);
  const float zg1 = sigmoidf_(z1 + bih[H + j1] + bhh[H + j1]);
  const float ng0 = tanhf(nx0 + bih[2 * H + j0] + rg0 * (nh0 + bhh[2 * H + j0]));
  const float ng1 = tanhf(nx1 + bih[2 * H + j1] + rg1 * (nh1 + bhh[2 * H + j1]));
  const float hp0 = hT[(size_t)j0 * B + b];
  const float hp1 = hT[(size_t)j1 * B + b];
  hout[(size_t)j0 * B + b] = (1.0f - zg0) * ng0 + zg0 * hp0;
  hout[(size_t)j1 * B + b] = (1.0f - zg1) * ng1 + zg1 * hp1;
}

// MLP1: 256 blocks, 16 rows/block, 2 rows/thread. PHI adds z-part (post-flow).
template<bool PHI>
__device__ __forceinline__ void mlp1F_(
    int blk2, const float* __restrict__ hin, const float* __restrict__ zcur,
    const float* __restrict__ W, const float* __restrict__ bias,
    float* __restrict__ outT) {
  const int t = threadIdx.x;
  const int col = t & 31;
  const int q = t >> 5;
  const int bg = blk2 & 7;
  const int b = bg * 32 + col;
  const int j0 = (blk2 >> 3) * 16 + q * 2;
  constexpr int Kv = PHI ? (H + Z) : H;
  const float* w0 = W + (size_t)j0 * Kv;
  const float* w1 = W + (size_t)(j0 + 1) * Kv;

  float a0c = 0.f, a1c = 0.f;
  #pragma unroll 2
  for (int k = 0; k < H; k += 4) {
    const float a0 = hin[(size_t)(k + 0) * B + b];
    const float a1 = hin[(size_t)(k + 1) * B + b];
    const float a2 = hin[(size_t)(k + 2) * B + b];
    const float a3 = hin[(size_t)(k + 3) * B + b];
    const float4 v0 = *(const float4*)(w0 + k);
    const float4 v1 = *(const float4*)(w1 + k);
    a0c = fmaf(v0.x, a0, fmaf(v0.y, a1, fmaf(v0.z, a2, fmaf(v0.w, a3, a0c))));
    a1c = fmaf(v1.x, a0, fmaf(v1.y, a1, fmaf(v1.z, a2, fmaf(v1.w, a3, a1c))));
  }
  if (PHI && zcur != nullptr) {
    #pragma unroll
    for (int zk = 0; zk < Z; ++zk) {
      const float a = zcur[(size_t)zk * B + b];
      a0c = fmaf(w0[H + zk], a, a0c);
      a1c = fmaf(w1[H + zk], a, a1c);
    }
  }
  outT[(size_t)j0 * B + b] = fmaxf(a0c + bias[j0], 0.f);
  outT[(size_t)(j0 + 1) * B + b] = fmaxf(a1c + bias[j0 + 1], 0.f);
}

// z head + flows: 8 blocks (blk==bg). 32 (loc,scale) rows; thread q handles
// z = {2q, 2q+1}. Flows run once per column on lanes t<32; stores post-flow z.
__device__ __forceinline__ void zheadF_(
    int bg, const float* __restrict__ h1T,
    const float* __restrict__ Wzl, const float* __restrict__ bzl,
    const float* __restrict__ Wzs, const float* __restrict__ bzs,
    const float* __restrict__ eps_t, float* __restrict__ z_out,
    const float* pu, const float* pw, const float* pb,
    float* kld_acc, float* ldsZ) {
  const int t = threadIdx.x;
  const int col = t & 31;
  const int q = t >> 5;
  const int b = bg * 32 + col;
  const int zz = q * 2;
  const float* w0 = Wzl + (size_t)zz * D;
  const float* w1 = Wzs + (size_t)zz * D;
  const float* w2 = Wzl + (size_t)(zz + 1) * D;
  const float* w3 = Wzs + (size_t)(zz + 1) * D;

  float a0 = 0.f, a1 = 0.f, a2 = 0.f, a3 = 0.f;
  #pragma unroll 2
  for (int k = 0; k < D; k += 4) {
    const float h0 = h1T[(size_t)(k + 0) * B + b];
    const float h1 = h1T[(size_t)(k + 1) * B + b];
    const float h2 = h1T[(size_t)(k + 2) * B + b];
    const float h3 = h1T[(size_t)(k + 3) * B + b];
    const float4 v0 = *(const float4*)(w0 + k);
    const float4 v1 = *(const float4*)(w1 + k);
    const float4 v2 = *(const float4*)(w2 + k);
    const float4 v3 = *(const float4*)(w3 + k);
    a0 = fmaf(v0.x, h0, fmaf(v0.y, h1, fmaf(v0.z, h2, fmaf(v0.w, h3, a0))));
    a1 = fmaf(v1.x, h0, fmaf(v1.y, h1, fmaf(v1.z, h2, fmaf(v1.w, h3, a1))));
    a2 = fmaf(v2.x, h0, fmaf(v2.y, h1, fmaf(v2.z, h2, fmaf(v2.w, h3, a2))));
    a3 = fmaf(v3.x, h0, fmaf(v3.y, h1, fmaf(v3.z, h2, fmaf(v3.w, h3, a3))));
  }
  float kacc = 0.f;
  {
    const float loc = a0 + bzl[zz];
    const float sc = softplusf_(a1 + bzs[zz]) + 1e-6f;
    ldsZ[zz * 32 + col] = loc + sc * eps_t[b * Z + zz];
    kacc -= logf(sc);
  }
  {
    const float loc = a2 + bzl[zz + 1];
    const float sc = softplusf_(a3 + bzs[zz + 1]) + 1e-6f;
    ldsZ[(zz + 1) * 32 + col] = loc + sc * eps_t[b * Z + zz + 1];
    kacc -= logf(sc);
  }
  __syncthreads();
  float v = kacc;
  if (t < 32) {
    float zv[Z];
    #pragma unroll
    for (int i2 = 0; i2 < Z; ++i2) zv[i2] = ldsZ[i2 * 32 + t];
    const float ld = flows_dev(zv, pu, pw, pb);
    #pragma unroll
    for (int i2 = 0; i2 < Z; ++i2) z_out[(size_t)i2 * B + bg * 32 + t] = zv[i2];
    v -= ld;
  }
  waveReduceAtomicAdd(kld_acc, v, t);
}

// y head: 16 blocks, 2 per bg (half in {0,1}); features [half*19, half*19+19).
__device__ __forceinline__ void yheadF_(
    int bg, int half, int ty, const float* __restrict__ g1T,
    const float* __restrict__ Wyl, const float* __restrict__ byl,
    const float* __restrict__ Wys, const float* __restrict__ bys,
    const float* __restrict__ xT, float* __restrict__ out_yloc,
    float* recon_acc) {
  const int t = threadIdx.x;
  const int col = t & 31;
  const int q = t >> 5;
  const int b = bg * 32 + col;
  const int fLo = half * 19;
  const int fLim = (fLo + 19 < F) ? (fLo + 19) : F;
  const int f0 = fLo + q * 3;

  float accL[3] = {0.f, 0.f, 0.f}, accS[3] = {0.f, 0.f, 0.f};
  const float* wl[3];
  const float* ws[3];
  #pragma unroll
  for (int j = 0; j < 3; ++j) {
    const int fc = (f0 + j < F) ? (f0 + j) : 0;
    wl[j] = Wyl + (size_t)fc * D;
    ws[j] = Wys + (size_t)fc * D;
  }
  #pragma unroll 2
  for (int k = 0; k < D; k += 4) {
    const float g0 = g1T[(size_t)(k + 0) * B + b];
    const float g1 = g1T[(size_t)(k + 1) * B + b];
    const float g2 = g1T[(size_t)(k + 2) * B + b];
    const float g3 = g1T[(size_t)(k + 3) * B + b];
    #pragma unroll
    for (int j = 0; j < 3; ++j) {
      const float4 vl = *(const float4*)(wl[j] + k);
      const float4 vs = *(const float4*)(ws[j] + k);
      accL[j] = fmaf(vl.x, g0, fmaf(vl.y, g1, fmaf(vl.z, g2, fmaf(vl.w, g3, accL[j]))));
      accS[j] = fmaf(vs.x, g0, fmaf(vs.y, g1, fmaf(vs.z, g2, fmaf(vs.w, g3, accS[j]))));
    }
  }
  float nl = 0.f;
  #pragma unroll
  for (int j = 0; j < 3; ++j) {
    const int f = f0 + j;
    if (f < fLim) {
      const float loc = accL[j] + byl[f];
      const float scl = softplusf_(accS[j] + bys[f]) + 1e-6f;
      out_yloc[((size_t)b * L + ty) * F + f] = loc;
      const float xv = xT[((size_t)ty * F + f) * B + b];
      const float d = (xv - loc) / scl;
      nl += 0.5f * d * d + logf(scl) + 0.5f * LOG2PI_F;
    }
  }
  waveReduceAtomicAdd(recon_acc, nl, t);
}

// ====================== SLOW PATH (R6, sc1) ================================

template<bool THETA>
__device__ __forceinline__ void gru_phase(
    int blk2, const float* __restrict__ xin, const float* __restrict__ hT,
    const float* __restrict__ Wih, const float* __restrict__ Whh,
    const float* __restrict__ bih, const float* __restrict__ bhh,
    float* __restrict__ hout,
    const float* pu, const float* pw, const float* pb, float* kld_acc,
    int w0h, float (&red)[4][4][8][64]) {
  const int tid = threadIdx.x;
  const int lane = tid & 63;
  const int wv = __builtin_amdgcn_readfirstlane(tid >> 6);
  const int j0 = (blk2 >> 2) * 8;
  const int b0 = (blk2 & 3) * 64;
  const int b = b0 + lane;
  constexpr int K1 = THETA ? Z : F;

  float accR[8], accZ[8], accNX[8], accNH[8];
  #pragma unroll
  for (int r = 0; r < 8; ++r) { accR[r] = 0.f; accZ[r] = 0.f; accNX[r] = 0.f; accNH[r] = 0.f; }

  float zv[Z];
  float ld = 0.0f;

  if (wv == 0) {
    const float* wr = Wih + (size_t)(0 * H + j0) * K1;
    const float* wz = Wih + (size_t)(1 * H + j0) * K1;
    const float* wn = Wih + (size_t)(2 * H + j0) * K1;
    if (THETA) {
      #pragma unroll
      for (int i = 0; i < Z; ++i) zv[i] = aload_(xin + i * B + b);
      ld = flows_dev(zv, pu, pw, pb);
      #pragma unroll
      for (int k = 0; k < Z; k += 4) {
        #pragma unroll
        for (int r = 0; r < 8; ++r) {
          const float4 w0 = *(const float4*)(wr + r * K1 + k);
          const float4 w1 = *(const float4*)(wz + r * K1 + k);
          const float4 w2 = *(const float4*)(wn + r * K1 + k);
          accR[r]  = fmaf(w0.x, zv[k], fmaf(w0.y, zv[k+1], fmaf(w0.z, zv[k+2], fmaf(w0.w, zv[k+3], accR[r]))));
          accZ[r]  = fmaf(w1.x, zv[k], fmaf(w1.y, zv[k+1], fmaf(w1.z, zv[k+2], fmaf(w1.w, zv[k+3], accZ[r]))));
          accNX[r] = fmaf(w2.x, zv[k], fmaf(w2.y, zv[k+1], fmaf(w2.z, zv[k+2], fmaf(w2.w, zv[k+3], accNX[r]))));
        }
      }
    } else {
      for (int k = 0; k < K1; ++k) {
        float a = xin[k * B + b];
        #pragma unroll
        for (int r = 0; r < 8; ++r) {
          accR[r]  = fmaf(wr[r * K1 + k], a, accR[r]);
          accZ[r]  = fmaf(wz[r * K1 + k], a, accZ[r]);
          accNX[r] = fmaf(wn[r * K1 + k], a, accNX[r]);
        }
      }
    }
  }

  const int rest = (H - w0h) / 3;
  const int hlo = (wv == 0) ? 0 : w0h + (wv - 1) * rest;
  const int hhi = (wv == 0) ? w0h : hlo + rest;
  {
    const float* vr = Whh + (size_t)(0 * H + j0) * H;
    const float* vz = Whh + (size_t)(1 * H + j0) * H;
    const float* vn = Whh + (size_t)(2 * H + j0) * H;
    #pragma unroll 2
    for (int k = hlo; k < hhi; k += 4) {
      const float a0 = aload_(hT + (size_t)(k + 0) * B + b);
      const float a1 = aload_(hT + (size_t)(k + 1) * B + b);
      const float a2 = aload_(hT + (size_t)(k + 2) * B + b);
      const float a3 = aload_(hT + (size_t)(k + 3) * B + b);
      #pragma unroll
      for (int r = 0; r < 8; ++r) {
        const float4 w0 = *(const float4*)(vr + (size_t)r * H + k);
        const float4 w1 = *(const float4*)(vz + (size_t)r * H + k);
        const float4 w2 = *(const float4*)(vn + (size_t)r * H + k);
        accR[r]  = fmaf(w0.x, a0, fmaf(w0.y, a1, fmaf(w0.z, a2, fmaf(w0.w, a3, accR[r]))));
        accZ[r]  = fmaf(w1.x, a0, fmaf(w1.y, a1, fmaf(w1.z, a2, fmaf(w1.w, a3, accZ[r]))));
        accNH[r] = fmaf(w2.x, a0, fmaf(w2.y, a1, fmaf(w2.z, a2, fmaf(w2.w, a3, accNH[r]))));
      }
    }
  }

  #pragma unroll
  for (int r = 0; r < 8; ++r) {
    red[wv][0][r][lane] = accR[r];
    red[wv][1][r][lane] = accZ[r];
    red[wv][2][r][lane] = accNX[r];
    red[wv][3][r][lane] = accNH[r];
  }

  if (THETA) {
    if (wv == 0 && j0 == 0) {
      waveReduceAtomicAdd(kld_acc, -ld, lane);
    }
  }

  __syncthreads();

  #pragma unroll
  for (int it = tid; it < 512; it += 256) {
    const int r = it >> 6, l = it & 63;
    float sR = 0.f, sZ = 0.f, sNX = 0.f, sNH = 0.f;
    #pragma unroll
    for (int w = 0; w < 4; ++w) {
      sR  += red[w][0][r][l];
      sZ  += red[w][1][r][l];
      sNX += red[w][2][r][l];
      sNH += red[w][3][r][l];
    }
    const int j = j0 + r;
    const int bb = b0 + l;
    const float rg = sigmoidf_(sR + bih[j] + bhh[j]);
    const float zg = sigmoidf_(sZ + bih[H + j] + bhh[H + j]);
    const float ng = tanhf(sNX + bih[2 * H + j] + rg * (sNH + bhh[2 * H + j]));
    const float hp = aload_(hT + (size_t)j * B + bb);
    astore_(hout + (size_t)j * B + bb, (1.0f - zg) * ng + zg * hp);
  }
}

__device__ __forceinline__ void lin8_phase(
    int blk2, const float* __restrict__ A1, int K1v,
    const float* __restrict__ W, const float* __restrict__ bias,
    float* __restrict__ outp, int relu, float* shbase) {
  const int tid = threadIdx.x;
  const int lane = tid & 63;
  const int wv = __builtin_amdgcn_readfirstlane(tid >> 6);
  const int r0 = (blk2 >> 2) * 8;
  const int b0 = (blk2 & 3) * 64;
  const int b = b0 + lane;
  const int Kv = K1v;
  const int klo = wv * (Kv >> 2);
  const int khi = klo + (Kv >> 2);

  float acc[8];
  #pragma unroll
  for (int r = 0; r < 8; ++r) acc[r] = 0.f;

  const float* wbase = W + (size_t)r0 * Kv;
  #pragma unroll 4
  for (int k = klo; k < khi; k += 4) {
    const float a0 = aload_(A1 + (size_t)(k + 0) * B + b);
    const float a1 = aload_(A1 + (size_t)(k + 1) * B + b);
    const float a2 = aload_(A1 + (size_t)(k + 2) * B + b);
    const float a3 = aload_(A1 + (size_t)(k + 3) * B + b);
    #pragma unroll
    for (int r = 0; r < 8; ++r) {
      const float4 w4 = *(const float4*)(wbase + (size_t)r * Kv + k);
      acc[r] = fmaf(w4.x, a0, fmaf(w4.y, a1, fmaf(w4.z, a2, fmaf(w4.w, a3, acc[r]))));
    }
  }

  float* red = shbase;
  #pragma unroll
  for (int r = 0; r < 8; ++r) red[(wv * 8 + r) * 64 + lane] = acc[r];
  __syncthreads();

  #pragma unroll
  for (int it = tid; it < 512; it += 256) {
    int r = it >> 6, l = it & 63;
    float s = red[(0 * 8 + r) * 64 + l] + red[(1 * 8 + r) * 64 + l]
            + red[(2 * 8 + r) * 64 + l] + red[(3 * 8 + r) * 64 + l] + bias[r0 + r];
    if (relu) s = fmaxf(s, 0.f);
    astore_(outp + (size_t)(r0 + r) * B + b0 + l, s);
  }
}

__device__ __forceinline__ void mlp1_phi_phase(
    int blk2, const float* __restrict__ hphiT, const float* __restrict__ z0prev,
    const float* __restrict__ W, const float* __restrict__ bias,
    float* __restrict__ h1T,
    const float* pu, const float* pw, const float* pb, float* shbase) {
  const int tid = threadIdx.x;
  const int lane = tid & 63;
  const int wv = __builtin_amdgcn_readfirstlane(tid >> 6);
  const int r0 = (blk2 >> 2) * 8;
  const int b0 = (blk2 & 3) * 64;
  const int b = b0 + lane;
  constexpr int Kv = H + Z;
  const int klo = wv * 140;
  const int khi = (wv == 3) ? H : klo + 140;

  float acc[8];
  #pragma unroll
  for (int r = 0; r < 8; ++r) acc[r] = 0.f;

  const float* wbase = W + (size_t)r0 * Kv;
  #pragma unroll 4
  for (int k = klo; k < khi; k += 4) {
    const float a0 = aload_(hphiT + (size_t)(k + 0) * B + b);
    const float a1 = aload_(hphiT + (size_t)(k + 1) * B + b);
    const float a2 = aload_(hphiT + (size_t)(k + 2) * B + b);
    const float a3 = aload_(hphiT + (size_t)(k + 3) * B + b);
    #pragma unroll
    for (int r = 0; r < 8; ++r) {
      const float4 w4 = *(const float4*)(wbase + (size_t)r * Kv + k);
      acc[r] = fmaf(w4.x, a0, fmaf(w4.y, a1, fmaf(w4.z, a2, fmaf(w4.w, a3, acc[r]))));
    }
  }
  if (wv == 3 && z0prev != nullptr) {
    float zv[Z];
    #pragma unroll
    for (int i = 0; i < Z; ++i) zv[i] = aload_(z0prev + i * B + b);
    flows_dev(zv, pu, pw, pb);
    #pragma unroll
    for (int i = 0; i < Z; i += 4) {
      #pragma unroll
      for (int r = 0; r < 8; ++r) {
        const float4 w4 = *(const float4*)(wbase + (size_t)r * Kv + H + i);
        acc[r] = fmaf(w4.x, zv[i], fmaf(w4.y, zv[i+1], fmaf(w4.z, zv[i+2], fmaf(w4.w, zv[i+3], acc[r]))));
      }
    }
  }

  float* red = shbase;
  #pragma unroll
  for (int r = 0; r < 8; ++r) red[(wv * 8 + r) * 64 + lane] = acc[r];
  __syncthreads();

  #pragma unroll
  for (int it = tid; it < 512; it += 256) {
    int r = it >> 6, l = it & 63;
    float s = red[(0 * 8 + r) * 64 + l] + red[(1 * 8 + r) * 64 + l]
            + red[(2 * 8 + r) * 64 + l] + red[(3 * 8 + r) * 64 + l] + bias[r0 + r];
    s = fmaxf(s, 0.f);
    astore_(h1T + (size_t)(r0 + r) * B + b0 + l, s);
  }
}

__device__ __forceinline__ void zhead_phase(
    int blk2, const float* __restrict__ h1T,
    const float* __restrict__ Wzl, const float* __restrict__ bzl,
    const float* __restrict__ Wzs, const float* __restrict__ bzs,
    const float* __restrict__ eps_t, float* __restrict__ z0T,
    float* kld_acc, float* shbase) {
  const int tid = threadIdx.x;
  const int lane = tid & 63;
  const int wv = __builtin_amdgcn_readfirstlane(tid >> 6);
  const int z0q = (blk2 >> 2) * 4;
  const int b0 = (blk2 & 3) * 64;
  const int b = b0 + lane;
  const int klo = wv * (D >> 2), khi = klo + (D >> 2);

  const float* wp[8];
  #pragma unroll
  for (int i = 0; i < 8; ++i) {
    int zz = z0q + (i >> 1);
    wp[i] = ((i & 1) ? Wzs : Wzl) + (size_t)zz * D;
  }
  float acc[8];
  #pragma unroll
  for (int i = 0; i < 8; ++i) acc[i] = 0.f;
  #pragma unroll 4
  for (int k = klo; k < khi; k += 4) {
    const float a0 = aload_(h1T + (size_t)(k + 0) * B + b);
    const float a1 = aload_(h1T + (size_t)(k + 1) * B + b);
    const float a2 = aload_(h1T + (size_t)(k + 2) * B + b);
    const float a3 = aload_(h1T + (size_t)(k + 3) * B + b);
    #pragma unroll
    for (int i = 0; i < 8; ++i) {
      const float4 w4 = *(const float4*)(wp[i] + k);
      acc[i] = fmaf(w4.x, a0, fmaf(w4.y, a1, fmaf(w4.z, a2, fmaf(w4.w, a3, acc[i]))));
    }
  }

  float* red = shbase;
  #pragma unroll
  for (int i = 0; i < 8; ++i) red[(wv * 8 + i) * 64 + lane] = acc[i];
  __syncthreads();

  int zi = tid >> 6, l = tid & 63;
  int zz = z0q + zi;
  int bb = b0 + l;
  float sl = red[(0 * 8 + 2 * zi) * 64 + l] + red[(1 * 8 + 2 * zi) * 64 + l]
           + red[(2 * 8 + 2 * zi) * 64 + l] + red[(3 * 8 + 2 * zi) * 64 + l] + bzl[zz];
  float ss = red[(0 * 8 + 2 * zi + 1) * 64 + l] + red[(1 * 8 + 2 * zi + 1) * 64 + l]
           + red[(2 * 8 + 2 * zi + 1) * 64 + l] + red[(3 * 8 + 2 * zi + 1) * 64 + l] + bzs[zz];
  float scale = softplusf_(ss) + 1e-6f;
  float ez = eps_t[bb * Z + zz];
  astore_(z0T + zz * B + bb, sl + scale * ez);
  waveReduceAtomicAdd(kld_acc, -logf(scale), tid);
}

__device__ __forceinline__ void yhead_phase(
    int blk2, int t, const float* __restrict__ g1T,
    const float* __restrict__ Wyl, const float* __restrict__ byl,
    const float* __restrict__ Wys, const float* __restrict__ bys,
    const float* __restrict__ xT, float* __restrict__ out_yloc,
    float* recon_acc, float* shbase) {
  const int tid = threadIdx.x;
  const int lane = tid & 63;
  const int wv = __builtin_amdgcn_readfirstlane(tid >> 6);
  const int f0 = (blk2 >> 2) * 4;
  const int b0 = (blk2 & 3) * 64;
  const int b = b0 + lane;
  const int klo = wv * (D >> 2), khi = klo + (D >> 2);

  const float* wp[8];
  #pragma unroll
  for (int i = 0; i < 8; ++i) {
    int ff = f0 + (i >> 1);
    int fc = ff < F ? ff : 0;
    wp[i] = ((i & 1) ? Wys : Wyl) + (size_t)fc * D;
  }
  float acc[8];
  #pragma unroll
  for (int i = 0; i < 8; ++i) acc[i] = 0.f;
  #pragma unroll 4
  for (int k = klo; k < khi; k += 4) {
    const float a0 = aload_(g1T + (size_t)(k + 0) * B + b);
    const float a1 = aload_(g1T + (size_t)(k + 1) * B + b);
    const float a2 = aload_(g1T + (size_t)(k + 2) * B + b);
    const float a3 = aload_(g1T + (size_t)(k + 3) * B + b);
    #pragma unroll
    for (int i = 0; i < 8; ++i) {
      const float4 w4 = *(const float4*)(wp[i] + k);
      acc[i] = fmaf(w4.x, a0, fmaf(w4.y, a1, fmaf(w4.z, a2, fmaf(w4.w, a3, acc[i]))));
    }
  }

  float* red = shbase;
  #pragma unroll
  for (int i = 0; i < 8; ++i) red[(wv * 8 + i) * 64 + lane] = acc[i];
  __syncthreads();

  int fi = tid >> 6, l = tid & 63;
  int ff = f0 + fi;
  int bb = b0 + l;
  float nl = 0.0f;
  if (ff < F) {
    float loc = red[(0 * 8 + 2 * fi) * 64 + l] + red[(1 * 8 + 2 * fi) * 64 + l]
              + red[(2 * 8 + 2 * fi) * 64 + l] + red[(3 * 8 + 2 * fi) * 64 + l] + byl[ff];
    float sp = red[(0 * 8 + 2 * fi + 1) * 64 + l] + red[(1 * 8 + 2 * fi + 1) * 64 + l]
             + red[(2 * 8 + 2 * fi + 1) * 64 + l] + red[(3 * 8 + 2 * fi + 1) * 64 + l] + bys[ff];
    float scale = softplusf_(sp) + 1e-6f;
    out_yloc[((size_t)bb * L + t) * F + ff] = loc;
    float xv = xT[((size_t)t * F + ff) * B + bb];
    float d = (xv - loc) / scale;
    nl = 0.5f * d * d + logf(scale) + 0.5f * LOG2PI_F;
  }
  waveReduceAtomicAdd(recon_acc, nl, tid);
}

// ---------------- persistent kernel ----------------
struct PP {
  const float *xT, *eps_z;
  const float *phi_Wih, *phi_Whh, *phi_bih, *phi_bhh, *phi_W1, *phi_b1;
  const float *th_Wih, *th_Whh, *th_bih, *th_bhh, *th_W1, *th_b1;
  const float *Wzl, *bzl, *Wzs, *bzs, *Wyl, *byl, *Wys, *bys;
  const float *pu, *pw, *pb;
  float *phi0, *phi1, *th0, *th1, *z0a, *z0b, *h1T, *g1T, *acc, *out;
  uint32_t* bar;
};

__global__ __launch_bounds__(256, 2) void k_persist(PP P) {
  __shared__ float red[4][4][8][64];  // 32 KB slow path; fast path uses 2 KB
  float* sh = &red[0][0][0][0];
  const int blk = blockIdx.x;
  uint32_t n = 0;

  // ---- XCD-placement check: fast path requires physical XCD == blk & 7 ----
  {
    uint32_t xcc;
    asm volatile("s_getreg_b32 %0, hwreg(20, 0, 4)" : "=s"(xcc));
    if (threadIdx.x == 0 && (int)xcc != (blk & 7))
      __hip_atomic_store(&P.bar[8], 1u, __ATOMIC_RELAXED, __HIP_MEMORY_SCOPE_AGENT);
  }
  ++n; gsync_(P.bar, blk, n);
  const bool fast =
      (__hip_atomic_load(&P.bar[8], __ATOMIC_RELAXED, __HIP_MEMORY_SCOPE_AGENT) == 0u);

  if (fast) {
    // ============ FAST: XCD-local batch groups, plain L2 traffic ============
    for (int i = 0; i <= L + 2; ++i) {
      const bool hasPhi = (i < L);
      const bool hasTh  = (i >= 2 && i <= L + 1);
      const bool hasZ   = (i >= 1 && i <= L);
      const bool hasY   = (i >= 3);

      const float* xt    = P.xT + (size_t)(hasPhi ? i : 0) * F * B;
      const float* phi_c = (i & 1) ? P.phi1 : P.phi0;   // phi_h(i-1)
      float*       phi_n = (i & 1) ? P.phi0 : P.phi1;   // phi_h(i)
      const float* z_in  = (i & 1) ? P.z0b : P.z0a;     // z(i-2) (post-flow)
      const float* th_c  = (i & 1) ? P.th0 : P.th1;     // th_h(i-3)
      float*       th_n  = (i & 1) ? P.th1 : P.th0;     // th_h(i-2)
      float*       z_out = (i & 1) ? P.z0a : P.z0b;     // z(i-1) (post-flow)

      // ---- phase A: phiGRU(i) | thGRU(i-2) | zhead+flows(i-1) | yhead(i-3)
      l1inv_();
      if (blk < 256) {
        if (hasPhi)
          gruF_<false>(blk, xt, phi_c, P.phi_Wih, P.phi_Whh, P.phi_bih,
                       P.phi_bhh, phi_n);
        if (blk < 8) {
          if (hasZ)
            zheadF_(blk & 7, P.h1T, P.Wzl, P.bzl, P.Wzs, P.bzs,
                    P.eps_z + (size_t)(i - 1) * B * Z, z_out,
                    P.pu, P.pw, P.pb, P.acc, sh);
        } else if (blk < 24) {
          if (hasY)
            yheadF_(blk & 7, (blk - 8) >> 3, i - 3, P.g1T, P.Wyl, P.byl,
                    P.Wys, P.bys, P.xT, P.out, P.acc + 1);
        }
      } else {
        if (hasTh)
          gruF_<true>(blk - 256, z_in, th_c, P.th_Wih, P.th_Whh, P.th_bih,
                      P.th_bhh, th_n);
      }
      ++n; gsync_(P.bar, blk, n);

      // ---- phase B: phiMLP1(i) | thMLP1(i-2)
      l1inv_();
      if (blk < 256) {
        if (hasPhi)
          mlp1F_<true>(blk, phi_n, (i >= 1) ? z_out : nullptr,
                       P.phi_W1, P.phi_b1, P.h1T);
      } else {
        if (hasTh)
          mlp1F_<false>(blk - 256, th_n, nullptr, P.th_W1, P.th_b1, P.g1T);
      }
      ++n; gsync_(P.bar, blk, n);
    }
  } else {
    // ============ SLOW: R6 sc1 path (placement-independent) ============
    for (int i = 0; i <= L + 2; ++i) {
      const bool hasPhi = (i < L);
      const bool hasTh  = (i >= 2 && i <= L + 1);
      const bool hasZ   = (i >= 1 && i <= L);
      const bool hasY   = (i >= 3);

      const float* xt     = P.xT + (size_t)(hasPhi ? i : 0) * F * B;
      const float* phi_c  = (i & 1) ? P.phi1 : P.phi0;
      float*       phi_n  = (i & 1) ? P.phi0 : P.phi1;
      const float* z0_in  = (i & 1) ? P.z0b : P.z0a;
      const float* th_c   = (i & 1) ? P.th0 : P.th1;
      float*       th_n   = (i & 1) ? P.th1 : P.th0;
      float*       z0_out = (i & 1) ? P.z0a : P.z0b;

      if (blk < 256) {
        if (hasPhi)
          gru_phase<false>(blk, xt, phi_c, P.phi_Wih, P.phi_Whh, P.phi_bih,
                           P.phi_bhh, phi_n, nullptr, nullptr, nullptr, nullptr,
                           104, red);
        if (blk < 56) {
          __syncthreads();
          if (blk < 16) {
            if (hasZ)
              zhead_phase(blk, P.h1T, P.Wzl, P.bzl, P.Wzs, P.bzs,
                          P.eps_z + (size_t)(i - 1) * B * Z, z0_out, P.acc, sh);
          } else {
            if (hasY)
              yhead_phase(blk - 16, i - 3, P.g1T, P.Wyl, P.byl, P.Wys, P.bys,
                          P.xT, P.out, P.acc + 1, sh);
          }
        }
      } else {
        if (hasTh)
          gru_phase<true>(blk - 256, z0_in, th_c, P.th_Wih, P.th_Whh, P.th_bih,
                          P.th_bhh, th_n, P.pu, P.pw, P.pb, P.acc, 56, red);
      }
      ++n; gsync_(P.bar, blk, n);

      if (blk < 256) {
        if (hasPhi)
          mlp1_phi_phase(blk, phi_n, (i >= 1) ? z0_out : nullptr,
                         P.phi_W1, P.phi_b1, P.h1T, P.pu, P.pw, P.pb, sh);
      } else {
        if (hasTh)
          lin8_phase(blk - 256, th_n, H, P.th_W1, P.th_b1, P.g1T, 1, sh);
      }
      ++n; gsync_(P.bar, blk, n);
    }
  }
}

}  // namespace

extern "C" void kernel_launch(void* const* d_in, const int* in_sizes, int n_in,
                              void* d_out, int out_size, void* d_ws, size_t ws_size,
                              hipStream_t stream) {
  const float* x        = (const float*)d_in[0];
  const float* phi_Wih  = (const float*)d_in[1];
  const float* phi_Whh  = (const float*)d_in[2];
  const float* phi_bih  = (const float*)d_in[3];
  const float* phi_bhh  = (const float*)d_in[4];
  const float* phi_W1   = (const float*)d_in[5];
  const float* phi_b1   = (const float*)d_in[6];
  const float* phi_W2   = (const float*)d_in[7];
  const float* phi_b2   = (const float*)d_in[8];
  const float* zloc_W   = (const float*)d_in[9];
  const float* zloc_b   = (const float*)d_in[10];
  const float* zscale_W = (const float*)d_in[11];
  const float* zscale_b = (const float*)d_in[12];
  const float* pu       = (const float*)d_in[13];
  const float* pw       = (const float*)d_in[14];
  const float* pb       = (const float*)d_in[15];
  const float* th_Wih   = (const float*)d_in[16];
  const float* th_Whh   = (const float*)d_in[17];
  const float* th_bih   = (const float*)d_in[18];
  const float* th_bhh   = (const float*)d_in[19];
  const float* th_W1    = (const float*)d_in[20];
  const float* th_b1    = (const float*)d_in[21];
  const float* th_W2    = (const float*)d_in[22];
  const float* th_b2    = (const float*)d_in[23];
  const float* xloc_W   = (const float*)d_in[24];
  const float* xloc_b   = (const float*)d_in[25];
  const float* xscale_W = (const float*)d_in[26];
  const float* xscale_b = (const float*)d_in[27];

  float* out = (float*)d_out;
  float* ws = (float*)d_ws;

  // workspace layout (floats)
  float* acc   = ws;                        // [0]=kld, [1]=recon
  uint32_t* bar = (uint32_t*)(ws + 64);     // 2048 dwords; bar[8] = slow-flag
  float* eps_z = ws + 64 + 2048;            // LBZ
  float* xT    = eps_z + LBZ;               // LFB
  float* phi0  = xT + LFB;                  // HB
  float* phi1  = phi0 + HB;                 // HB
  float* th0   = phi1 + HB;                 // HB
  float* th1   = th0 + HB;                  // HB
  float* z0a   = th1 + HB;                  // ZB
  float* z0b   = z0a + ZB;                  // ZB
  float* h1T   = z0b + ZB;                  // DB
  float* g1T   = h1T + DB;                  // DB
  float* Wzl   = g1T + DB;                  // Z*D
  float* Wzs   = Wzl + Z * D;               // Z*D
  float* bzl   = Wzs + Z * D;               // 64
  float* bzs   = bzl + 64;                  // 64
  float* Wyl   = bzs + 64;                  // F*D
  float* Wys   = Wyl + F * D;               // F*D
  float* byl   = Wys + F * D;               // 64
  float* bys   = byl + 64;                  // 64

  hipMemsetAsync(ws, 0, (64 + 2048) * sizeof(float), stream);   // acc + barrier
  hipMemsetAsync(phi0, 0, (size_t)HB * sizeof(float), stream);  // phi_h(-1)
  hipMemsetAsync(th1, 0, (size_t)HB * sizeof(float), stream);   // th_h(-1)

  // JAX PRNG: key(42)=(0,42); split -> kz, kp
  uint32_t a0, a1, b0, b1;
  threefry2x32_(0u, 42u, 0u, 2u, a0, a1);
  threefry2x32_(0u, 42u, 1u, 3u, b0, b1);
  const uint32_t kz0 = a0, kz1 = b0, kp0 = a1, kp1 = b1;

  k_transpose_x<<<(B * L * F) / 256, 256, 0, stream>>>(x, xT);
  k_noise<<<HALF / 256, 256, 0, stream>>>(eps_z, acc, kz0, kz1, kp0, kp1);

  // Compose linear MLP2 into the z/y heads: Wc = headW @ W2, bc = headW @ b2 + headb.
  k_compose<<<Z, 256, 0, stream>>>(zloc_W, zloc_b, phi_W2, phi_b2, Wzl, bzl);
  k_compose<<<Z, 256, 0, stream>>>(zscale_W, zscale_b, phi_W2, phi_b2, Wzs, bzs);
  k_compose<<<F, 256, 0, stream>>>(xloc_W, xloc_b, th_W2, th_b2, Wyl, byl);
  k_compose<<<F, 256, 0, stream>>>(xscale_W, xscale_b, th_W2, th_b2, Wys, bys);

  PP P;
  P.xT = xT; P.eps_z = eps_z;
  P.phi_Wih = phi_Wih; P.phi_Whh = phi_Whh; P.phi_bih = phi_bih; P.phi_bhh = phi_bhh;
  P.phi_W1 = phi_W1; P.phi_b1 = phi_b1;
  P.th_Wih = th_Wih; P.th_Whh = th_Whh; P.th_bih = th_bih; P.th_bhh = th_bhh;
  P.th_W1 = th_W1; P.th_b1 = th_b1;
  P.Wzl = Wzl; P.bzl = bzl; P.Wzs = Wzs; P.bzs = bzs;
  P.Wyl = Wyl; P.byl = byl; P.Wys = Wys; P.bys = bys;
  P.pu = pu; P.pw = pw; P.pb = pb;
  P.phi0 = phi0; P.phi1 = phi1; P.th0 = th0; P.th1 = th1;
  P.z0a = z0a; P.z0b = z0b; P.h1T = h1T; P.g1T = g1T;
  P.acc = acc; P.out = out; P.bar = bar;

  k_persist<<<GRIDN, 256, 0, stream>>>(P);

  k_finalize<<<1, 1, 0, stream>>>(acc, out);
}

// Round 8
// 31516.922 us; speedup vs baseline: 1.3864x; 1.3864x over previous
//
#include <hip/hip_runtime.h>
#include <stdint.h>
#include <math.h>

namespace {

constexpr int B = 256, L = 256, F = 38, H = 512, D = 512, Z = 16, NF = 20;
constexpr float LOG2PI_F = 1.8378770664093453f;
constexpr int LBZ = L * B * Z;      // 1048576
constexpr int HALF = LBZ / 2;       // 524288
constexpr int HB = H * B;           // 131072
constexpr int DB = D * B;           // 131072
constexpr int ZB = Z * B;           // 4096
constexpr int LFB = L * F * B;      // 2490368

// ---------------- math helpers ----------------

__device__ __forceinline__ float sigmoidf_(float x) {
  return 1.0f / (1.0f + expf(-x));
}
__device__ __forceinline__ float softplusf_(float x) {
  return fmaxf(x, 0.0f) + log1pf(expf(-fabsf(x)));
}

__device__ __forceinline__ void waveReduceAtomicAdd(float* dst, float v, int tid) {
  #pragma unroll
  for (int off = 32; off > 0; off >>= 1) v += __shfl_down(v, off, 64);
  if ((tid & 63) == 0) atomicAdd(dst, v);
}

// ---------------- threefry2x32 (JAX-compatible) ----------------

__host__ __device__ inline uint32_t rotl32_(uint32_t x, int d) {
  return (x << d) | (x >> (32 - d));
}

__host__ __device__ inline void threefry2x32_(uint32_t k0, uint32_t k1,
                                              uint32_t x0, uint32_t x1,
                                              uint32_t& o0, uint32_t& o1) {
  const uint32_t ks2 = k0 ^ k1 ^ 0x1BD11BDAu;
  uint32_t v0 = x0 + k0;
  uint32_t v1 = x1 + k1;
#define TF_RND(r) { v0 += v1; v1 = rotl32_(v1, r); v1 ^= v0; }
  TF_RND(13) TF_RND(15) TF_RND(26) TF_RND(6)
  v0 += k1;  v1 += ks2 + 1u;
  TF_RND(17) TF_RND(29) TF_RND(16) TF_RND(24)
  v0 += ks2; v1 += k0 + 2u;
  TF_RND(13) TF_RND(15) TF_RND(26) TF_RND(6)
  v0 += k0;  v1 += k1 + 3u;
  TF_RND(17) TF_RND(29) TF_RND(16) TF_RND(24)
  v0 += k1;  v1 += ks2 + 4u;
  TF_RND(13) TF_RND(15) TF_RND(26) TF_RND(6)
  v0 += ks2; v1 += k0 + 5u;
#undef TF_RND
  o0 = v0; o1 = v1;
}

__device__ __forceinline__ float erfinv_f_(float x) {
  float w = -log1pf(-x * x);
  float p;
  if (w < 5.0f) {
    w -= 2.5f;
    p = 2.81022636e-08f;
    p = fmaf(p, w, 3.43273939e-07f);
    p = fmaf(p, w, -3.5233877e-06f);
    p = fmaf(p, w, -4.39150654e-06f);
    p = fmaf(p, w, 0.00021858087f);
    p = fmaf(p, w, -0.00125372503f);
    p = fmaf(p, w, -0.00417768164f);
    p = fmaf(p, w, 0.246640727f);
    p = fmaf(p, w, 1.50140941f);
  } else {
    w = sqrtf(w) - 3.0f;
    p = -0.000200214257f;
    p = fmaf(p, w, 0.000100950558f);
    p = fmaf(p, w, 0.00134934322f);
    p = fmaf(p, w, -0.00367342844f);
    p = fmaf(p, w, 0.00573950773f);
    p = fmaf(p, w, -0.0076224613f);
    p = fmaf(p, w, 0.00943887047f);
    p = fmaf(p, w, 1.00167406f);
    p = fmaf(p, w, 2.83297682f);
  }
  return p * x;
}

__device__ __forceinline__ float bits_to_normal_(uint32_t bits) {
  uint32_t m = (bits >> 9) | 0x3f800000u;
  float f = __uint_as_float(m) - 1.0f;
  float u = f * 2.0f + (-0.99999994f);
  u = fmaxf(-0.99999994f, u);
  return 1.41421356f * erfinv_f_(u);
}

// planar flows for one batch column (per-lane), returns logdet; zv updated in place
__device__ __forceinline__ float flows_dev(float zv[Z], const float* __restrict__ pu,
                                           const float* __restrict__ pw,
                                           const float* __restrict__ pb) {
  float ld = 0.0f;
  for (int f = 0; f < NF; ++f) {
    const float* w = pw + f * Z;
    const float* u = pu + f * Z;
    float wn2 = 0.0f, wu = 0.0f;
    #pragma unroll
    for (int i = 0; i < Z; ++i) { wn2 = fmaf(w[i], w[i], wn2); wu = fmaf(w[i], u[i], wu); }
    float coef = (softplusf_(wu) - 1.0f - wu) / wn2;
    float a_in = pb[f];
    #pragma unroll
    for (int i = 0; i < Z; ++i) a_in = fmaf(zv[i], w[i], a_in);
    float a = tanhf(a_in);
    float uw = 0.0f;
    #pragma unroll
    for (int i = 0; i < Z; ++i) {
      float uh = fmaf(coef, w[i], u[i]);
      uw = fmaf(uh, w[i], uw);
      zv[i] = fmaf(uh, a, zv[i]);
    }
    ld += logf(fabsf(1.0f + (1.0f - a * a) * uw) + 1e-12f);
  }
  return ld;
}

// ---------------- small utility kernels ----------------

__global__ __launch_bounds__(256) void k_transpose_x(const float* __restrict__ x,
                                                     float* __restrict__ xT) {
  int idx = blockIdx.x * blockDim.x + threadIdx.x;  // over B*L*F
  int f = idx % F;
  int t = (idx / F) % L;
  int b = idx / (F * L);
  xT[(t * F + f) * B + b] = x[idx];
}

__global__ __launch_bounds__(256) void k_noise(float* __restrict__ eps_z,
                                               float* __restrict__ kld_acc,
                                               uint32_t kz0, uint32_t kz1,
                                               uint32_t kp0, uint32_t kp1) {
  int i = blockIdx.x * blockDim.x + threadIdx.x;  // [0, HALF)
  uint32_t a0, a1, b0, b1;
  threefry2x32_(kz0, kz1, (uint32_t)i, (uint32_t)(i + HALF), a0, a1);
  float ez0 = bits_to_normal_(a0);
  float ez1 = bits_to_normal_(a1);
  eps_z[i] = ez0;
  eps_z[i + HALF] = ez1;
  threefry2x32_(kp0, kp1, (uint32_t)i, (uint32_t)(i + HALF), b0, b1);
  float ep0 = bits_to_normal_(b0);
  float ep1 = bits_to_normal_(b1);
  float local = -0.5f * (ez0 * ez0 + ez1 * ez1) + 0.5f * (ep0 * ep0 + ep1 * ep1);
  waveReduceAtomicAdd(kld_acc, local, threadIdx.x);
}

__global__ void k_finalize(const float* __restrict__ acc, float* __restrict__ out) {
  out[(size_t)B * L * F] = acc[1];      // recon
  out[(size_t)B * L * F + 1] = acc[0];  // kld
}

// ---------------- weight composition (once per launch) ----------------
// Wc[r][k] = sum_j A[r][j] * W2[j][k]; bc[r] = sum_j A[r][j]*b2[j] + bA[r]
__global__ __launch_bounds__(256) void k_compose(
    const float* __restrict__ A, const float* __restrict__ bA,
    const float* __restrict__ W2, const float* __restrict__ b2,
    float* __restrict__ Wc, float* __restrict__ bc) {
  const int r = blockIdx.x;
  const int k = threadIdx.x;
  float acc0 = 0.f, acc1 = 0.f;
  for (int j = 0; j < D; ++j) {
    float a = A[(size_t)r * D + j];          // wave-uniform
    acc0 = fmaf(a, W2[(size_t)j * D + k], acc0);
    acc1 = fmaf(a, W2[(size_t)j * D + k + 256], acc1);
  }
  Wc[(size_t)r * D + k] = acc0;
  Wc[(size_t)r * D + k + 256] = acc1;
  float accb = 0.f;
  for (int j = k; j < D; j += 256) accb += A[(size_t)r * D + j] * b2[j];
  __shared__ float s[256];
  s[k] = accb;
  __syncthreads();
  for (int off = 128; off > 0; off >>= 1) {
    if (k < off) s[k] += s[k + off];
    __syncthreads();
  }
  if (k == 0) bc[r] = s[0] + bA[r];
}

// ---------------- constant pointer bundle ----------------
struct CW {
  const float *phi_Wih, *phi_Whh, *phi_bih, *phi_bhh, *phi_W1, *phi_b1;
  const float *th_Wih, *th_Whh, *th_bih, *th_bhh, *th_W1, *th_b1;
  const float *Wzl, *bzl, *Wzs, *bzs, *Wyl, *byl, *Wys, *bys;
  const float *pu, *pw, *pb, *xT;
  float *acc, *out;
};

// ---------------- 8-row GRU block (R3-proven pattern, K1 templated) --------
// blk2 in [0,256): j0=(blk2>>2)*8 rows, b0=(blk2&3)*64 cols. 4 waves:
// wave0 does x/z-part (K1) + w0h h-rows; waves 1..3 split the rest.
// sh: red [4 waves][4 qty][8 rows][64 lanes] = 8192 floats.
template<int K1>
__device__ __forceinline__ void gru8(
    int blk2, const float* __restrict__ xin, const float* __restrict__ hT,
    const float* __restrict__ Wih, const float* __restrict__ Whh,
    const float* __restrict__ bih, const float* __restrict__ bhh,
    float* __restrict__ hout, int w0h, float* sh) {
  const int tid = threadIdx.x;
  const int lane = tid & 63;
  const int wv = __builtin_amdgcn_readfirstlane(tid >> 6);
  const int j0 = (blk2 >> 2) * 8;
  const int b0 = (blk2 & 3) * 64;
  const int b = b0 + lane;

  float accR[8], accZ[8], accNX[8], accNH[8];
  #pragma unroll
  for (int r = 0; r < 8; ++r) { accR[r] = 0.f; accZ[r] = 0.f; accNX[r] = 0.f; accNH[r] = 0.f; }

  if (wv == 0) {
    const float* wr = Wih + (size_t)(0 * H + j0) * K1;
    const float* wz = Wih + (size_t)(1 * H + j0) * K1;
    const float* wn = Wih + (size_t)(2 * H + j0) * K1;
    #pragma unroll 2
    for (int k = 0; k < K1; ++k) {
      const float a = xin[(size_t)k * B + b];
      #pragma unroll
      for (int r = 0; r < 8; ++r) {
        accR[r]  = fmaf(wr[r * K1 + k], a, accR[r]);
        accZ[r]  = fmaf(wz[r * K1 + k], a, accZ[r]);
        accNX[r] = fmaf(wn[r * K1 + k], a, accNX[r]);
      }
    }
  }

  const int rest = (H - w0h) / 3;
  const int hlo = (wv == 0) ? 0 : w0h + (wv - 1) * rest;
  const int hhi = (wv == 0) ? w0h : hlo + rest;
  {
    const float* vr = Whh + (size_t)(0 * H + j0) * H;
    const float* vz = Whh + (size_t)(1 * H + j0) * H;
    const float* vn = Whh + (size_t)(2 * H + j0) * H;
    #pragma unroll 2
    for (int k = hlo; k < hhi; k += 4) {
      const float a0 = hT[(size_t)(k + 0) * B + b];
      const float a1 = hT[(size_t)(k + 1) * B + b];
      const float a2 = hT[(size_t)(k + 2) * B + b];
      const float a3 = hT[(size_t)(k + 3) * B + b];
      #pragma unroll
      for (int r = 0; r < 8; ++r) {
        const float4 w0 = *(const float4*)(vr + (size_t)r * H + k);
        const float4 w1 = *(const float4*)(vz + (size_t)r * H + k);
        const float4 w2 = *(const float4*)(vn + (size_t)r * H + k);
        accR[r]  = fmaf(w0.x, a0, fmaf(w0.y, a1, fmaf(w0.z, a2, fmaf(w0.w, a3, accR[r]))));
        accZ[r]  = fmaf(w1.x, a0, fmaf(w1.y, a1, fmaf(w1.z, a2, fmaf(w1.w, a3, accZ[r]))));
        accNH[r] = fmaf(w2.x, a0, fmaf(w2.y, a1, fmaf(w2.z, a2, fmaf(w2.w, a3, accNH[r]))));
      }
    }
  }

  #pragma unroll
  for (int r = 0; r < 8; ++r) {
    sh[((wv * 4 + 0) * 8 + r) * 64 + lane] = accR[r];
    sh[((wv * 4 + 1) * 8 + r) * 64 + lane] = accZ[r];
    sh[((wv * 4 + 2) * 8 + r) * 64 + lane] = accNX[r];
    sh[((wv * 4 + 3) * 8 + r) * 64 + lane] = accNH[r];
  }
  __syncthreads();

  #pragma unroll
  for (int it = tid; it < 512; it += 256) {
    const int r = it >> 6, l = it & 63;
    float sR = 0.f, sZ = 0.f, sNX = 0.f, sNH = 0.f;
    #pragma unroll
    for (int w = 0; w < 4; ++w) {
      sR  += sh[((w * 4 + 0) * 8 + r) * 64 + l];
      sZ  += sh[((w * 4 + 1) * 8 + r) * 64 + l];
      sNX += sh[((w * 4 + 2) * 8 + r) * 64 + l];
      sNH += sh[((w * 4 + 3) * 8 + r) * 64 + l];
    }
    const int j = j0 + r;
    const int bb = b0 + l;
    const float rg = sigmoidf_(sR + bih[j] + bhh[j]);
    const float zg = sigmoidf_(sZ + bih[H + j] + bhh[H + j]);
    const float ng = tanhf(sNX + bih[2 * H + j] + rg * (sNH + bhh[2 * H + j]));
    const float hp = hT[(size_t)j * B + bb];
    hout[(size_t)j * B + bb] = (1.0f - zg) * ng + zg * hp;
  }
}

// ---------------- linear 8-row block (theta MLP1) ----------------
__device__ __forceinline__ void lin8(
    int blk2, const float* __restrict__ A1,
    const float* __restrict__ W, const float* __restrict__ bias,
    float* __restrict__ outp, float* sh) {
  const int tid = threadIdx.x;
  const int lane = tid & 63;
  const int wv = __builtin_amdgcn_readfirstlane(tid >> 6);
  const int r0 = (blk2 >> 2) * 8;
  const int b0 = (blk2 & 3) * 64;
  const int b = b0 + lane;
  const int klo = wv * (H >> 2);
  const int khi = klo + (H >> 2);

  float acc[8];
  #pragma unroll
  for (int r = 0; r < 8; ++r) acc[r] = 0.f;

  const float* wbase = W + (size_t)r0 * H;
  #pragma unroll 4
  for (int k = klo; k < khi; k += 4) {
    const float a0 = A1[(size_t)(k + 0) * B + b];
    const float a1 = A1[(size_t)(k + 1) * B + b];
    const float a2 = A1[(size_t)(k + 2) * B + b];
    const float a3 = A1[(size_t)(k + 3) * B + b];
    #pragma unroll
    for (int r = 0; r < 8; ++r) {
      const float4 w4 = *(const float4*)(wbase + (size_t)r * H + k);
      acc[r] = fmaf(w4.x, a0, fmaf(w4.y, a1, fmaf(w4.z, a2, fmaf(w4.w, a3, acc[r]))));
    }
  }

  #pragma unroll
  for (int r = 0; r < 8; ++r) sh[(wv * 8 + r) * 64 + lane] = acc[r];
  __syncthreads();

  #pragma unroll
  for (int it = tid; it < 512; it += 256) {
    int r = it >> 6, l = it & 63;
    float s = sh[(0 * 8 + r) * 64 + l] + sh[(1 * 8 + r) * 64 + l]
            + sh[(2 * 8 + r) * 64 + l] + sh[(3 * 8 + r) * 64 + l] + bias[r0 + r];
    outp[(size_t)(r0 + r) * B + b0 + l] = fmaxf(s, 0.f);
  }
}

// ---------------- phi MLP1 with inline z-head + flows ----------------
// h1(i-1) = relu(W1 @ [phi_h(i-1); z(i-2)] + b1), where z(i-2) =
// flows(zloc(h1(i-2)) + sigma*eps) is computed IN-BLOCK (inline z-head).
// rb==0 blocks publish z(i-2) to global and add the KLD terms.
// sh layout: [0,2048) main red [4][8][64]; [2048,10240) zred [4][32][64];
// after zred is dead: zfin 16x64 @2048, zpost 16x64 @3072 (overlay).
__device__ __forceinline__ void mlp1z(
    int blk2, const CW& C, const float* __restrict__ hphi,
    const float* __restrict__ h1prev, const float* __restrict__ epsT,
    float* __restrict__ h1out, float* __restrict__ zOut,
    bool doMain, bool doZ, float* sh) {
  const int tid = threadIdx.x;
  const int lane = tid & 63;
  const int wv = __builtin_amdgcn_readfirstlane(tid >> 6);
  const int rb = blk2 >> 2;
  const int r0 = rb * 8;
  const int b0 = (blk2 & 3) * 64;
  const int b = b0 + lane;
  constexpr int Kv = H + Z;  // 528
  float* redM = sh;            // [4][8][64]
  float* zred = sh + 2048;     // [4][32][64]
  float* zfin = sh + 2048;     // overlay (z0 values) [16][64]
  float* zpost = sh + 3072;    // overlay (post-flow z) [16][64]

  float acc[8];
  #pragma unroll
  for (int r = 0; r < 8; ++r) acc[r] = 0.f;

  const float* wbase = C.phi_W1 + (size_t)r0 * Kv;
  if (doMain) {
    const int klo = wv * 140;
    const int khi = (wv == 3) ? H : klo + 140;   // wave3: 420..512
    #pragma unroll 4
    for (int k = klo; k < khi; k += 4) {
      const float a0 = hphi[(size_t)(k + 0) * B + b];
      const float a1 = hphi[(size_t)(k + 1) * B + b];
      const float a2 = hphi[(size_t)(k + 2) * B + b];
      const float a3 = hphi[(size_t)(k + 3) * B + b];
      #pragma unroll
      for (int r = 0; r < 8; ++r) {
        const float4 w4 = *(const float4*)(wbase + (size_t)r * Kv + k);
        acc[r] = fmaf(w4.x, a0, fmaf(w4.y, a1, fmaf(w4.z, a2, fmaf(w4.w, a3, acc[r]))));
      }
    }
    if (!doZ || wv != 3) {   // wave3 defers its write until z-part added
      #pragma unroll
      for (int r = 0; r < 8; ++r) redM[(wv * 8 + r) * 64 + lane] = acc[r];
    }
  }

  float kpart = 0.f;
  if (doZ) {
    // ---- inline z-head partial dots over h1(i-2), K-split 4 ways ----
    float za[32];
    #pragma unroll
    for (int zo = 0; zo < 32; ++zo) za[zo] = 0.f;
    const int kz0 = wv * 128;
    for (int k0 = kz0; k0 < kz0 + 128; k0 += 8) {
      float av[8];
      #pragma unroll
      for (int kk = 0; kk < 8; ++kk) av[kk] = h1prev[(size_t)(k0 + kk) * B + b];
      #pragma unroll
      for (int zi = 0; zi < 16; ++zi) {
        const float* wl = C.Wzl + (size_t)zi * D + k0;
        const float* ws = C.Wzs + (size_t)zi * D + k0;
        #pragma unroll
        for (int kk = 0; kk < 8; ++kk) {
          za[2 * zi]     = fmaf(wl[kk], av[kk], za[2 * zi]);
          za[2 * zi + 1] = fmaf(ws[kk], av[kk], za[2 * zi + 1]);
        }
      }
    }
    #pragma unroll
    for (int zo = 0; zo < 32; ++zo) zred[(wv * 32 + zo) * 64 + lane] = za[zo];
    __syncthreads();   // zred complete

    // ---- reduce -> z0 = loc + sigma*eps ; KLD -= log sigma ----
    float z0v[4];
    int zidx[4], cidx[4];
    #pragma unroll
    for (int m = 0; m < 4; ++m) {
      const int id = tid + m * 256;        // 1024 = 16 z x 64 cols
      const int zi = id >> 6, col = id & 63;
      zidx[m] = zi; cidx[m] = col;
      float loc = C.bzl[zi], sg = C.bzs[zi];
      #pragma unroll
      for (int w = 0; w < 4; ++w) {
        loc += zred[(w * 32 + 2 * zi) * 64 + col];
        sg  += zred[(w * 32 + 2 * zi + 1) * 64 + col];
      }
      const float sigma = softplusf_(sg) + 1e-6f;
      z0v[m] = loc + sigma * epsT[(size_t)(b0 + col) * Z + zi];
      kpart -= logf(sigma);
    }
    __syncthreads();   // all zred reads done (zfin overlays it)
    #pragma unroll
    for (int m = 0; m < 4; ++m) zfin[zidx[m] * 64 + cidx[m]] = z0v[m];
    __syncthreads();   // zfin ready

    // ---- flows (wave0, one column per lane) ----
    if (tid < 64) {
      float zv[Z];
      #pragma unroll
      for (int zi = 0; zi < Z; ++zi) zv[zi] = zfin[zi * 64 + tid];
      const float ld = flows_dev(zv, C.pu, C.pw, C.pb);
      #pragma unroll
      for (int zi = 0; zi < Z; ++zi) zpost[zi * 64 + tid] = zv[zi];
      if (rb == 0) {
        #pragma unroll
        for (int zi = 0; zi < Z; ++zi) zOut[(size_t)zi * B + b0 + tid] = zv[zi];
        kpart -= ld;
      }
    }
    __syncthreads();   // zpost ready

    if (doMain && wv == 3) {   // add z-part once, then store wave3 partials
      #pragma unroll
      for (int zi = 0; zi < Z; ++zi) {
        const float zp = zpost[zi * 64 + lane];
        #pragma unroll
        for (int r = 0; r < 8; ++r)
          acc[r] = fmaf(wbase[(size_t)r * Kv + H + zi], zp, acc[r]);
      }
      #pragma unroll
      for (int r = 0; r < 8; ++r) redM[(wv * 8 + r) * 64 + lane] = acc[r];
    }
    if (rb == 0) waveReduceAtomicAdd(C.acc, kpart, tid);
  }

  if (doMain) {
    __syncthreads();   // redM complete
    #pragma unroll
    for (int it = tid; it < 512; it += 256) {
      int r = it >> 6, l = it & 63;
      float s = redM[(0 * 8 + r) * 64 + l] + redM[(1 * 8 + r) * 64 + l]
              + redM[(2 * 8 + r) * 64 + l] + redM[(3 * 8 + r) * 64 + l]
              + C.phi_b1[r0 + r];
      h1out[(size_t)(r0 + r) * B + b0 + l] = fmaxf(s, 0.f);
    }
  }
}

// ---------------- y head (R1-proven): blk2 in [0,40) ----------------
__device__ __forceinline__ void yhead8(
    int blk2, int t, const CW& C, const float* __restrict__ g1T, float* sh) {
  const int tid = threadIdx.x;
  const int lane = tid & 63;
  const int wv = __builtin_amdgcn_readfirstlane(tid >> 6);
  const int f0 = (blk2 >> 2) * 4;
  const int b0 = (blk2 & 3) * 64;
  const int b = b0 + lane;
  const int klo = wv * (D >> 2), khi = klo + (D >> 2);

  const float* wp[8];
  #pragma unroll
  for (int i = 0; i < 8; ++i) {
    int ff = f0 + (i >> 1);
    int fc = ff < F ? ff : 0;
    wp[i] = ((i & 1) ? C.Wys : C.Wyl) + (size_t)fc * D;
  }
  float acc[8];
  #pragma unroll
  for (int i = 0; i < 8; ++i) acc[i] = 0.f;
  #pragma unroll 4
  for (int k = klo; k < khi; k += 4) {
    const float a0 = g1T[(size_t)(k + 0) * B + b];
    const float a1 = g1T[(size_t)(k + 1) * B + b];
    const float a2 = g1T[(size_t)(k + 2) * B + b];
    const float a3 = g1T[(size_t)(k + 3) * B + b];
    #pragma unroll
    for (int i = 0; i < 8; ++i) {
      const float4 w4 = *(const float4*)(wp[i] + k);
      acc[i] = fmaf(w4.x, a0, fmaf(w4.y, a1, fmaf(w4.z, a2, fmaf(w4.w, a3, acc[i]))));
    }
  }

  #pragma unroll
  for (int i = 0; i < 8; ++i) sh[(wv * 8 + i) * 64 + lane] = acc[i];
  __syncthreads();

  int fi = tid >> 6, l = tid & 63;
  int ff = f0 + fi;
  int bb = b0 + l;
  float nl = 0.0f;
  if (ff < F) {
    float loc = sh[(0 * 8 + 2 * fi) * 64 + l] + sh[(1 * 8 + 2 * fi) * 64 + l]
              + sh[(2 * 8 + 2 * fi) * 64 + l] + sh[(3 * 8 + 2 * fi) * 64 + l] + C.byl[ff];
    float sp = sh[(0 * 8 + 2 * fi + 1) * 64 + l] + sh[(1 * 8 + 2 * fi + 1) * 64 + l]
             + sh[(2 * 8 + 2 * fi + 1) * 64 + l] + sh[(3 * 8 + 2 * fi + 1) * 64 + l] + C.bys[ff];
    float scale = softplusf_(sp) + 1e-6f;
    C.out[((size_t)bb * L + t) * F + ff] = loc;
    float xv = C.xT[((size_t)t * F + ff) * B + bb];
    float d = (xv - loc) / scale;
    nl = 0.5f * d * d + logf(scale) + 0.5f * LOG2PI_F;
  }
  waveReduceAtomicAdd(C.acc + 1, nl, tid);
}

// ---------------- mega step kernel: ONE launch per timestep ----------------
// L(i): phiGRU(i)[0,256) | phiMLP1(i-1)+inline-z(i-2)[256,512)
//       | thGRU(i-3)[512,768) | thMLP1(i-4)[768,1024) | yhead(i-5)[1024,1064)
// All cross-unit deps resolved by PREVIOUS launches (ring-2 buffers).
__global__ __launch_bounds__(256) void k_step(
    CW C, int i,
    const float* xin, const float* phiPrev, float* phiCur,
    const float* h1prev, float* h1cur, float* zOut, const float* zIn,
    const float* thPrev, float* thCur, float* g1cur, const float* g1prev,
    const float* epsT) {
  __shared__ float sh[10240];  // 40 KB
  const int blk = blockIdx.x;

  if (blk < 256) {
    if (i < L)
      gru8<F>(blk, xin, phiPrev, C.phi_Wih, C.phi_Whh, C.phi_bih, C.phi_bhh,
              phiCur, 104, sh);
  } else if (blk < 512) {
    const bool doMain = (i >= 1 && i <= L);
    const bool doZ = (i >= 2 && i <= L + 1);
    if ((doMain || doZ) && (doMain || ((blk - 256) >> 2) == 0))
      mlp1z(blk - 256, C, phiPrev, h1prev, epsT, h1cur, zOut, doMain, doZ, sh);
  } else if (blk < 768) {
    if (i >= 3 && i <= L + 2)
      gru8<Z>(blk - 512, zIn, thPrev, C.th_Wih, C.th_Whh, C.th_bih, C.th_bhh,
              thCur, 116, sh);
  } else if (blk < 1024) {
    if (i >= 4 && i <= L + 3)
      lin8(blk - 768, thPrev, C.th_W1, C.th_b1, g1cur, sh);
  } else {
    if (i >= 5)
      yhead8(blk - 1024, i - 5, C, g1prev, sh);
  }
}

}  // namespace

extern "C" void kernel_launch(void* const* d_in, const int* in_sizes, int n_in,
                              void* d_out, int out_size, void* d_ws, size_t ws_size,
                              hipStream_t stream) {
  const float* x        = (const float*)d_in[0];
  const float* phi_Wih  = (const float*)d_in[1];
  const float* phi_Whh  = (const float*)d_in[2];
  const float* phi_bih  = (const float*)d_in[3];
  const float* phi_bhh  = (const float*)d_in[4];
  const float* phi_W1   = (const float*)d_in[5];
  const float* phi_b1   = (const float*)d_in[6];
  const float* phi_W2   = (const float*)d_in[7];
  const float* phi_b2   = (const float*)d_in[8];
  const float* zloc_W   = (const float*)d_in[9];
  const float* zloc_b   = (const float*)d_in[10];
  const float* zscale_W = (const float*)d_in[11];
  const float* zscale_b = (const float*)d_in[12];
  const float* pu       = (const float*)d_in[13];
  const float* pw       = (const float*)d_in[14];
  const float* pb       = (const float*)d_in[15];
  const float* th_Wih   = (const float*)d_in[16];
  const float* th_Whh   = (const float*)d_in[17];
  const float* th_bih   = (const float*)d_in[18];
  const float* th_bhh   = (const float*)d_in[19];
  const float* th_W1    = (const float*)d_in[20];
  const float* th_b1    = (const float*)d_in[21];
  const float* th_W2    = (const float*)d_in[22];
  const float* th_b2    = (const float*)d_in[23];
  const float* xloc_W   = (const float*)d_in[24];
  const float* xloc_b   = (const float*)d_in[25];
  const float* xscale_W = (const float*)d_in[26];
  const float* xscale_b = (const float*)d_in[27];

  float* out = (float*)d_out;
  float* ws = (float*)d_ws;

  // workspace layout (floats)
  float* acc   = ws;                        // [0]=kld, [1]=recon
  float* eps_z = ws + 64;                   // LBZ
  float* xT    = eps_z + LBZ;               // LFB
  float* phi0  = xT + LFB;                  // HB  (phi_h ring)
  float* phi1  = phi0 + HB;                 // HB
  float* th0   = phi1 + HB;                 // HB  (th_h ring)
  float* th1   = th0 + HB;                  // HB
  float* z0a   = th1 + HB;                  // ZB  (post-flow z ring)
  float* z0b   = z0a + ZB;                  // ZB
  float* h1a   = z0b + ZB;                  // DB  (h1 ring)
  float* h1b   = h1a + DB;                  // DB
  float* g1a   = h1b + DB;                  // DB  (g1 ring)
  float* g1b   = g1a + DB;                  // DB
  float* Wzl   = g1b + DB;                  // Z*D
  float* Wzs   = Wzl + Z * D;               // Z*D
  float* bzl   = Wzs + Z * D;               // 64
  float* bzs   = bzl + 64;                  // 64
  float* Wyl   = bzs + 64;                  // F*D
  float* Wys   = Wyl + F * D;               // F*D
  float* byl   = Wys + F * D;               // 64
  float* bys   = byl + 64;                  // 64

  float* phiR[2] = {phi0, phi1};
  float* thR[2]  = {th0, th1};
  float* zR[2]   = {z0a, z0b};
  float* h1R[2]  = {h1a, h1b};
  float* g1R[2]  = {g1a, g1b};

  hipMemsetAsync(acc, 0, 64 * sizeof(float), stream);
  hipMemsetAsync(phi1, 0, (size_t)HB * sizeof(float), stream);  // phi_h(-1): slot 1
  hipMemsetAsync(th1, 0, (size_t)HB * sizeof(float), stream);   // th_h(-1): slot 1

  // JAX PRNG: key(42)=(0,42); split -> kz, kp
  uint32_t a0, a1, b0, b1;
  threefry2x32_(0u, 42u, 0u, 2u, a0, a1);
  threefry2x32_(0u, 42u, 1u, 3u, b0, b1);
  const uint32_t kz0 = a0, kz1 = b0, kp0 = a1, kp1 = b1;

  k_transpose_x<<<(B * L * F) / 256, 256, 0, stream>>>(x, xT);
  k_noise<<<HALF / 256, 256, 0, stream>>>(eps_z, acc, kz0, kz1, kp0, kp1);

  // Compose linear MLP2 into the z/y heads: Wc = headW @ W2, bc = headW @ b2 + headb.
  k_compose<<<Z, 256, 0, stream>>>(zloc_W, zloc_b, phi_W2, phi_b2, Wzl, bzl);
  k_compose<<<Z, 256, 0, stream>>>(zscale_W, zscale_b, phi_W2, phi_b2, Wzs, bzs);
  k_compose<<<F, 256, 0, stream>>>(xloc_W, xloc_b, th_W2, th_b2, Wyl, byl);
  k_compose<<<F, 256, 0, stream>>>(xscale_W, xscale_b, th_W2, th_b2, Wys, bys);

  CW C;
  C.phi_Wih = phi_Wih; C.phi_Whh = phi_Whh; C.phi_bih = phi_bih; C.phi_bhh = phi_bhh;
  C.phi_W1 = phi_W1; C.phi_b1 = phi_b1;
  C.th_Wih = th_Wih; C.th_Whh = th_Whh; C.th_bih = th_bih; C.th_bhh = th_bhh;
  C.th_W1 = th_W1; C.th_b1 = th_b1;
  C.Wzl = Wzl; C.bzl = bzl; C.Wzs = Wzs; C.bzs = bzs;
  C.Wyl = Wyl; C.byl = byl; C.Wys = Wys; C.bys = bys;
  C.pu = pu; C.pw = pw; C.pb = pb; C.xT = xT;
  C.acc = acc; C.out = out;

  // One launch per pipeline slot i:
  //   phiGRU(i) | phiMLP1(i-1)+inline-z(i-2) | thGRU(i-3) | thMLP1(i-4) | yhead(i-5)
  // Ring slots (all ring-2; every same-launch read/write pair uses opposite parity):
  //   phi: write i&1, read (i+1)&1        h1: write (i+1)&1, read i&1
  //   z:   write i&1, read (i+1)&1        th: write (i+1)&1, read i&1
  //   g1:  write i&1, read (i+1)&1
  for (int i = 0; i <= L + 4; ++i) {
    const float* xin     = xT + (size_t)((i < L) ? i : 0) * F * B;
    const float* phiPrev = phiR[(i + 1) & 1];
    float*       phiCur  = phiR[i & 1];
    const float* h1prev  = h1R[i & 1];
    float*       h1cur   = h1R[(i + 1) & 1];
    float*       zOut    = zR[i & 1];
    const float* zIn     = zR[(i + 1) & 1];
    const float* thPrev  = thR[i & 1];
    float*       thCur   = thR[(i + 1) & 1];
    float*       g1cur   = g1R[i & 1];
    const float* g1prev  = g1R[(i + 1) & 1];
    const float* epsT    = eps_z +
        (size_t)((i >= 2 && i <= L + 1) ? (i - 2) : 0) * B * Z;

    k_step<<<1064, 256, 0, stream>>>(C, i, xin, phiPrev, phiCur, h1prev, h1cur,
                                     zOut, zIn, thPrev, thCur, g1cur, g1prev,
                                     epsT);
  }

  k_finalize<<<1, 1, 0, stream>>>(acc, out);
}

// Round 10
// 29266.751 us; speedup vs baseline: 1.4930x; 1.0769x over previous
//
#include <hip/hip_runtime.h>
#include <stdint.h>
#include <math.h>

namespace {

constexpr int B = 256, L = 256, F = 38, H = 512, D = 512, Z = 16, NF = 20;
constexpr float LOG2PI_F = 1.8378770664093453f;
constexpr int LBZ = L * B * Z;      // 1048576
constexpr int HALF = LBZ / 2;       // 524288
constexpr int HB = H * B;           // 131072
constexpr int DB = D * B;           // 131072
constexpr int ZB = Z * B;           // 4096
constexpr int LFB = L * F * B;      // 2490368
constexpr int TC = 32;              // tail chunk (timesteps)

// ---------------- math helpers ----------------

__device__ __forceinline__ float sigmoidf_(float x) {
  return 1.0f / (1.0f + expf(-x));
}
__device__ __forceinline__ float softplusf_(float x) {
  return fmaxf(x, 0.0f) + log1pf(expf(-fabsf(x)));
}

__device__ __forceinline__ void waveReduceAtomicAdd(float* dst, float v, int tid) {
  #pragma unroll
  for (int off = 32; off > 0; off >>= 1) v += __shfl_down(v, off, 64);
  if ((tid & 63) == 0) atomicAdd(dst, v);
}

// XCD-aware (rb, bg) decode: row-block rb == blk2&7 (mod 8) so all 4
// batch-group copies of a row-block land on ONE XCD (blockIdx round-robin).
// Bijective blk2 in [0,256) -> (rb in [0,64), bg in [0,4)); harmless if the
// HW mapping differs (perf-only).
__device__ __forceinline__ void rbbg_(int blk2, int& rb, int& bg) {
  const int slot = blk2 >> 3;          // [0,32)
  rb = ((slot >> 2) << 3) + (blk2 & 7);
  bg = slot & 3;
}

// ---------------- threefry2x32 (JAX-compatible) ----------------

__host__ __device__ inline uint32_t rotl32_(uint32_t x, int d) {
  return (x << d) | (x >> (32 - d));
}

__host__ __device__ inline void threefry2x32_(uint32_t k0, uint32_t k1,
                                              uint32_t x0, uint32_t x1,
                                              uint32_t& o0, uint32_t& o1) {
  const uint32_t ks2 = k0 ^ k1 ^ 0x1BD11BDAu;
  uint32_t v0 = x0 + k0;
  uint32_t v1 = x1 + k1;
#define TF_RND(r) { v0 += v1; v1 = rotl32_(v1, r); v1 ^= v0; }
  TF_RND(13) TF_RND(15) TF_RND(26) TF_RND(6)
  v0 += k1;  v1 += ks2 + 1u;
  TF_RND(17) TF_RND(29) TF_RND(16) TF_RND(24)
  v0 += ks2; v1 += k0 + 2u;
  TF_RND(13) TF_RND(15) TF_RND(26) TF_RND(6)
  v0 += k0;  v1 += k1 + 3u;
  TF_RND(17) TF_RND(29) TF_RND(16) TF_RND(24)
  v0 += k1;  v1 += ks2 + 4u;
  TF_RND(13) TF_RND(15) TF_RND(26) TF_RND(6)
  v0 += ks2; v1 += k0 + 5u;
#undef TF_RND
  o0 = v0; o1 = v1;
}

__device__ __forceinline__ float erfinv_f_(float x) {
  float w = -log1pf(-x * x);
  float p;
  if (w < 5.0f) {
    w -= 2.5f;
    p = 2.81022636e-08f;
    p = fmaf(p, w, 3.43273939e-07f);
    p = fmaf(p, w, -3.5233877e-06f);
    p = fmaf(p, w, -4.39150654e-06f);
    p = fmaf(p, w, 0.00021858087f);
    p = fmaf(p, w, -0.00125372503f);
    p = fmaf(p, w, -0.00417768164f);
    p = fmaf(p, w, 0.246640727f);
    p = fmaf(p, w, 1.50140941f);
  } else {
    w = sqrtf(w) - 3.0f;
    p = -0.000200214257f;
    p = fmaf(p, w, 0.000100950558f);
    p = fmaf(p, w, 0.00134934322f);
    p = fmaf(p, w, -0.00367342844f);
    p = fmaf(p, w, 0.00573950773f);
    p = fmaf(p, w, -0.0076224613f);
    p = fmaf(p, w, 0.00943887047f);
    p = fmaf(p, w, 1.00167406f);
    p = fmaf(p, w, 2.83297682f);
  }
  return p * x;
}

__device__ __forceinline__ float bits_to_normal_(uint32_t bits) {
  uint32_t m = (bits >> 9) | 0x3f800000u;
  float f = __uint_as_float(m) - 1.0f;
  float u = f * 2.0f + (-0.99999994f);
  u = fmaxf(-0.99999994f, u);
  return 1.41421356f * erfinv_f_(u);
}

// planar flows for one batch column (per-lane), returns logdet; zv updated in place
__device__ __forceinline__ float flows_dev(float zv[Z], const float* __restrict__ pu,
                                           const float* __restrict__ pw,
                                           const float* __restrict__ pb) {
  float ld = 0.0f;
  for (int f = 0; f < NF; ++f) {
    const float* w = pw + f * Z;
    const float* u = pu + f * Z;
    float wn2 = 0.0f, wu = 0.0f;
    #pragma unroll
    for (int i = 0; i < Z; ++i) { wn2 = fmaf(w[i], w[i], wn2); wu = fmaf(w[i], u[i], wu); }
    float coef = (softplusf_(wu) - 1.0f - wu) / wn2;
    float a_in = pb[f];
    #pragma unroll
    for (int i = 0; i < Z; ++i) a_in = fmaf(zv[i], w[i], a_in);
    float a = tanhf(a_in);
    float uw = 0.0f;
    #pragma unroll
    for (int i = 0; i < Z; ++i) {
      float uh = fmaf(coef, w[i], u[i]);
      uw = fmaf(uh, w[i], uw);
      zv[i] = fmaf(uh, a, zv[i]);
    }
    ld += logf(fabsf(1.0f + (1.0f - a * a) * uw) + 1e-12f);
  }
  return ld;
}

// ---------------- small utility kernels ----------------

__global__ __launch_bounds__(256) void k_transpose_x(const float* __restrict__ x,
                                                     float* __restrict__ xT) {
  int idx = blockIdx.x * blockDim.x + threadIdx.x;  // over B*L*F
  int f = idx % F;
  int t = (idx / F) % L;
  int b = idx / (F * L);
  xT[(t * F + f) * B + b] = x[idx];
}

__global__ __launch_bounds__(256) void k_noise(float* __restrict__ eps_z,
                                               float* __restrict__ kld_acc,
                                               uint32_t kz0, uint32_t kz1,
                                               uint32_t kp0, uint32_t kp1) {
  int i = blockIdx.x * blockDim.x + threadIdx.x;  // [0, HALF)
  uint32_t a0, a1, b0, b1;
  threefry2x32_(kz0, kz1, (uint32_t)i, (uint32_t)(i + HALF), a0, a1);
  float ez0 = bits_to_normal_(a0);
  float ez1 = bits_to_normal_(a1);
  eps_z[i] = ez0;
  eps_z[i + HALF] = ez1;
  threefry2x32_(kp0, kp1, (uint32_t)i, (uint32_t)(i + HALF), b0, b1);
  float ep0 = bits_to_normal_(b0);
  float ep1 = bits_to_normal_(b1);
  float local = -0.5f * (ez0 * ez0 + ez1 * ez1) + 0.5f * (ep0 * ep0 + ep1 * ep1);
  waveReduceAtomicAdd(kld_acc, local, threadIdx.x);
}

__global__ void k_finalize(const float* __restrict__ acc, float* __restrict__ out) {
  out[(size_t)B * L * F] = acc[1];      // recon
  out[(size_t)B * L * F + 1] = acc[0];  // kld
}

// ---------------- weight composition (once per launch) ----------------
__global__ __launch_bounds__(256) void k_compose(
    const float* __restrict__ A, const float* __restrict__ bA,
    const float* __restrict__ W2, const float* __restrict__ b2,
    float* __restrict__ Wc, float* __restrict__ bc) {
  const int r = blockIdx.x;
  const int k = threadIdx.x;
  float acc0 = 0.f, acc1 = 0.f;
  for (int j = 0; j < D; ++j) {
    float a = A[(size_t)r * D + j];          // wave-uniform
    acc0 = fmaf(a, W2[(size_t)j * D + k], acc0);
    acc1 = fmaf(a, W2[(size_t)j * D + k + 256], acc1);
  }
  Wc[(size_t)r * D + k] = acc0;
  Wc[(size_t)r * D + k + 256] = acc1;
  float accb = 0.f;
  for (int j = k; j < D; j += 256) accb += A[(size_t)r * D + j] * b2[j];
  __shared__ float s[256];
  s[k] = accb;
  __syncthreads();
  for (int off = 128; off > 0; off >>= 1) {
    if (k < off) s[k] += s[k + off];
    __syncthreads();
  }
  if (k == 0) bc[r] = s[0] + bA[r];
}

// ---------------- constant pointer bundle ----------------
struct CW {
  const float *phi_Wih, *phi_Whh, *phi_bih, *phi_bhh, *phi_W1, *phi_b1;
  const float *th_Wih, *th_Whh, *th_bih, *th_bhh, *th_W1, *th_b1;
  const float *Wzl, *bzl, *Wzs, *bzs, *Wyl, *byl, *Wys, *bys;
  const float *pu, *pw, *pb, *xT;
  float *acc, *out;
};

// ---------------- 8-row GRU block (R8-proven; XCD-swizzled rb,bg) ----------
template<int K1>
__device__ __forceinline__ void gru8(
    int blk2, const float* __restrict__ xin, const float* __restrict__ hT,
    const float* __restrict__ Wih, const float* __restrict__ Whh,
    const float* __restrict__ bih, const float* __restrict__ bhh,
    float* __restrict__ hout, int w0h, float* sh) {
  const int tid = threadIdx.x;
  const int lane = tid & 63;
  const int wv = __builtin_amdgcn_readfirstlane(tid >> 6);
  int rb, bg;
  rbbg_(blk2, rb, bg);
  const int j0 = rb * 8;
  const int b0 = bg * 64;
  const int b = b0 + lane;

  float accR[8], accZ[8], accNX[8], accNH[8];
  #pragma unroll
  for (int r = 0; r < 8; ++r) { accR[r] = 0.f; accZ[r] = 0.f; accNX[r] = 0.f; accNH[r] = 0.f; }

  if (wv == 0) {
    const float* wr = Wih + (size_t)(0 * H + j0) * K1;
    const float* wz = Wih + (size_t)(1 * H + j0) * K1;
    const float* wn = Wih + (size_t)(2 * H + j0) * K1;
    #pragma unroll 2
    for (int k = 0; k < K1; ++k) {
      const float a = xin[(size_t)k * B + b];
      #pragma unroll
      for (int r = 0; r < 8; ++r) {
        accR[r]  = fmaf(wr[r * K1 + k], a, accR[r]);
        accZ[r]  = fmaf(wz[r * K1 + k], a, accZ[r]);
        accNX[r] = fmaf(wn[r * K1 + k], a, accNX[r]);
      }
    }
  }

  const int rest = (H - w0h) / 3;
  const int hlo = (wv == 0) ? 0 : w0h + (wv - 1) * rest;
  const int hhi = (wv == 0) ? w0h : hlo + rest;
  {
    const float* vr = Whh + (size_t)(0 * H + j0) * H;
    const float* vz = Whh + (size_t)(1 * H + j0) * H;
    const float* vn = Whh + (size_t)(2 * H + j0) * H;
    #pragma unroll 2
    for (int k = hlo; k < hhi; k += 4) {
      const float a0 = hT[(size_t)(k + 0) * B + b];
      const float a1 = hT[(size_t)(k + 1) * B + b];
      const float a2 = hT[(size_t)(k + 2) * B + b];
      const float a3 = hT[(size_t)(k + 3) * B + b];
      #pragma unroll
      for (int r = 0; r < 8; ++r) {
        const float4 w0 = *(const float4*)(vr + (size_t)r * H + k);
        const float4 w1 = *(const float4*)(vz + (size_t)r * H + k);
        const float4 w2 = *(const float4*)(vn + (size_t)r * H + k);
        accR[r]  = fmaf(w0.x, a0, fmaf(w0.y, a1, fmaf(w0.z, a2, fmaf(w0.w, a3, accR[r]))));
        accZ[r]  = fmaf(w1.x, a0, fmaf(w1.y, a1, fmaf(w1.z, a2, fmaf(w1.w, a3, accZ[r]))));
        accNH[r] = fmaf(w2.x, a0, fmaf(w2.y, a1, fmaf(w2.z, a2, fmaf(w2.w, a3, accNH[r]))));
      }
    }
  }

  #pragma unroll
  for (int r = 0; r < 8; ++r) {
    sh[((wv * 4 + 0) * 8 + r) * 64 + lane] = accR[r];
    sh[((wv * 4 + 1) * 8 + r) * 64 + lane] = accZ[r];
    sh[((wv * 4 + 2) * 8 + r) * 64 + lane] = accNX[r];
    sh[((wv * 4 + 3) * 8 + r) * 64 + lane] = accNH[r];
  }
  __syncthreads();

  #pragma unroll
  for (int it = tid; it < 512; it += 256) {
    const int r = it >> 6, l = it & 63;
    float sR = 0.f, sZ = 0.f, sNX = 0.f, sNH = 0.f;
    #pragma unroll
    for (int w = 0; w < 4; ++w) {
      sR  += sh[((w * 4 + 0) * 8 + r) * 64 + l];
      sZ  += sh[((w * 4 + 1) * 8 + r) * 64 + l];
      sNX += sh[((w * 4 + 2) * 8 + r) * 64 + l];
      sNH += sh[((w * 4 + 3) * 8 + r) * 64 + l];
    }
    const int j = j0 + r;
    const int bb = b0 + l;
    const float rg = sigmoidf_(sR + bih[j] + bhh[j]);
    const float zg = sigmoidf_(sZ + bih[H + j] + bhh[H + j]);
    const float ng = tanhf(sNX + bih[2 * H + j] + rg * (sNH + bhh[2 * H + j]));
    const float hp = hT[(size_t)j * B + bb];
    hout[(size_t)j * B + bb] = (1.0f - zg) * ng + zg * hp;
  }
}

// ---------------- phi MLP1 with inline z-head + flows (R8-proven) ----------
// h1(i-1) = relu(W1 @ [phi_h(i-1); z(i-2)] + b1), where z(i-2) =
// flows(zloc(h1(i-2)) + sigma*eps). rb==0 blocks publish z(i-2) + KLD terms.
// sh: [0,2048) redM; [2048,10240) zred; overlays zfin@2048, zpost@3072.
__device__ __forceinline__ void mlp1z(
    int blk2, const CW& C, const float* __restrict__ hphi,
    const float* __restrict__ h1prev, const float* __restrict__ epsT,
    float* __restrict__ h1out, float* __restrict__ zOut,
    bool doMain, bool doZ, float* sh) {
  const int tid = threadIdx.x;
  const int lane = tid & 63;
  const int wv = __builtin_amdgcn_readfirstlane(tid >> 6);
  int rb, bg;
  rbbg_(blk2, rb, bg);
  const int r0 = rb * 8;
  const int b0 = bg * 64;
  const int b = b0 + lane;
  constexpr int Kv = H + Z;  // 528
  float* redM = sh;            // [4][8][64]
  float* zred = sh + 2048;     // [4][32][64]
  float* zfin = sh + 2048;     // overlay [16][64]
  float* zpost = sh + 3072;    // overlay [16][64]

  float acc[8];
  #pragma unroll
  for (int r = 0; r < 8; ++r) acc[r] = 0.f;

  const float* wbase = C.phi_W1 + (size_t)r0 * Kv;
  if (doMain) {
    const int klo = wv * 140;
    const int khi = (wv == 3) ? H : klo + 140;   // wave3: 420..512
    #pragma unroll 4
    for (int k = klo; k < khi; k += 4) {
      const float a0 = hphi[(size_t)(k + 0) * B + b];
      const float a1 = hphi[(size_t)(k + 1) * B + b];
      const float a2 = hphi[(size_t)(k + 2) * B + b];
      const float a3 = hphi[(size_t)(k + 3) * B + b];
      #pragma unroll
      for (int r = 0; r < 8; ++r) {
        const float4 w4 = *(const float4*)(wbase + (size_t)r * Kv + k);
        acc[r] = fmaf(w4.x, a0, fmaf(w4.y, a1, fmaf(w4.z, a2, fmaf(w4.w, a3, acc[r]))));
      }
    }
    if (!doZ || wv != 3) {   // wave3 defers its write until z-part added
      #pragma unroll
      for (int r = 0; r < 8; ++r) redM[(wv * 8 + r) * 64 + lane] = acc[r];
    }
  }

  float kpart = 0.f;
  if (doZ) {
    // inline z-head partial dots over h1(i-2), K-split 4 ways
    float za[32];
    #pragma unroll
    for (int zo = 0; zo < 32; ++zo) za[zo] = 0.f;
    const int kz0 = wv * 128;
    for (int k0 = kz0; k0 < kz0 + 128; k0 += 8) {
      float av[8];
      #pragma unroll
      for (int kk = 0; kk < 8; ++kk) av[kk] = h1prev[(size_t)(k0 + kk) * B + b];
      #pragma unroll
      for (int zi = 0; zi < 16; ++zi) {
        const float* wl = C.Wzl + (size_t)zi * D + k0;
        const float* ws = C.Wzs + (size_t)zi * D + k0;
        #pragma unroll
        for (int kk = 0; kk < 8; ++kk) {
          za[2 * zi]     = fmaf(wl[kk], av[kk], za[2 * zi]);
          za[2 * zi + 1] = fmaf(ws[kk], av[kk], za[2 * zi + 1]);
        }
      }
    }
    #pragma unroll
    for (int zo = 0; zo < 32; ++zo) zred[(wv * 32 + zo) * 64 + lane] = za[zo];
    __syncthreads();   // zred complete

    float z0v[4];
    int zidx[4], cidx[4];
    #pragma unroll
    for (int m = 0; m < 4; ++m) {
      const int id = tid + m * 256;        // 1024 = 16 z x 64 cols
      const int zi = id >> 6, col = id & 63;
      zidx[m] = zi; cidx[m] = col;
      float loc = C.bzl[zi], sg = C.bzs[zi];
      #pragma unroll
      for (int w = 0; w < 4; ++w) {
        loc += zred[(w * 32 + 2 * zi) * 64 + col];
        sg  += zred[(w * 32 + 2 * zi + 1) * 64 + col];
      }
      const float sigma = softplusf_(sg) + 1e-6f;
      z0v[m] = loc + sigma * epsT[(size_t)(b0 + col) * Z + zi];
      kpart -= logf(sigma);
    }
    __syncthreads();   // all zred reads done (zfin overlays it)
    #pragma unroll
    for (int m = 0; m < 4; ++m) zfin[zidx[m] * 64 + cidx[m]] = z0v[m];
    __syncthreads();   // zfin ready

    if (tid < 64) {
      float zv[Z];
      #pragma unroll
      for (int zi = 0; zi < Z; ++zi) zv[zi] = zfin[zi * 64 + tid];
      const float ld = flows_dev(zv, C.pu, C.pw, C.pb);
      #pragma unroll
      for (int zi = 0; zi < Z; ++zi) zpost[zi * 64 + tid] = zv[zi];
      if (rb == 0) {
        #pragma unroll
        for (int zi = 0; zi < Z; ++zi) zOut[(size_t)zi * B + b0 + tid] = zv[zi];
        kpart -= ld;
      }
    }
    __syncthreads();   // zpost ready

    if (doMain && wv == 3) {
      #pragma unroll
      for (int zi = 0; zi < Z; ++zi) {
        const float zp = zpost[zi * 64 + lane];
        #pragma unroll
        for (int r = 0; r < 8; ++r)
          acc[r] = fmaf(wbase[(size_t)r * Kv + H + zi], zp, acc[r]);
      }
      #pragma unroll
      for (int r = 0; r < 8; ++r) redM[(wv * 8 + r) * 64 + lane] = acc[r];
    }
    if (rb == 0) waveReduceAtomicAdd(C.acc, kpart, tid);
  }

  if (doMain) {
    __syncthreads();   // redM complete
    #pragma unroll
    for (int it = tid; it < 512; it += 256) {
      int r = it >> 6, l = it & 63;
      float s = redM[(0 * 8 + r) * 64 + l] + redM[(1 * 8 + r) * 64 + l]
              + redM[(2 * 8 + r) * 64 + l] + redM[(3 * 8 + r) * 64 + l]
              + C.phi_b1[r0 + r];
      h1out[(size_t)(r0 + r) * B + b0 + l] = fmaxf(s, 0.f);
    }
  }
}

// ---------------- linear 8-row block (theta MLP1; unswizzled decode) -------
__device__ __forceinline__ void lin8(
    int blk2, const float* __restrict__ A1,
    const float* __restrict__ W, const float* __restrict__ bias,
    float* __restrict__ outp, float* sh) {
  const int tid = threadIdx.x;
  const int lane = tid & 63;
  const int wv = __builtin_amdgcn_readfirstlane(tid >> 6);
  const int r0 = (blk2 >> 2) * 8;
  const int b0 = (blk2 & 3) * 64;
  const int b = b0 + lane;
  const int klo = wv * (H >> 2);
  const int khi = klo + (H >> 2);

  float acc[8];
  #pragma unroll
  for (int r = 0; r < 8; ++r) acc[r] = 0.f;

  const float* wbase = W + (size_t)r0 * H;
  #pragma unroll 4
  for (int k = klo; k < khi; k += 4) {
    const float a0 = A1[(size_t)(k + 0) * B + b];
    const float a1 = A1[(size_t)(k + 1) * B + b];
    const float a2 = A1[(size_t)(k + 2) * B + b];
    const float a3 = A1[(size_t)(k + 3) * B + b];
    #pragma unroll
    for (int r = 0; r < 8; ++r) {
      const float4 w4 = *(const float4*)(wbase + (size_t)r * H + k);
      acc[r] = fmaf(w4.x, a0, fmaf(w4.y, a1, fmaf(w4.z, a2, fmaf(w4.w, a3, acc[r]))));
    }
  }

  #pragma unroll
  for (int r = 0; r < 8; ++r) sh[(wv * 8 + r) * 64 + lane] = acc[r];
  __syncthreads();

  #pragma unroll
  for (int it = tid; it < 512; it += 256) {
    int r = it >> 6, l = it & 63;
    float s = sh[(0 * 8 + r) * 64 + l] + sh[(1 * 8 + r) * 64 + l]
            + sh[(2 * 8 + r) * 64 + l] + sh[(3 * 8 + r) * 64 + l] + bias[r0 + r];
    outp[(size_t)(r0 + r) * B + b0 + l] = fmaxf(s, 0.f);
  }
}

// ---------------- y head (R1-proven): blk2 in [0,40) ----------------
__device__ __forceinline__ void yhead8(
    int blk2, int t, const CW& C, const float* __restrict__ g1T,
    long sG1, float* sh) {
  const int tid = threadIdx.x;
  const int lane = tid & 63;
  const int wv = __builtin_amdgcn_readfirstlane(tid >> 6);
  const int f0 = (blk2 >> 2) * 4;
  const int b0 = (blk2 & 3) * 64;
  const int b = b0 + lane;
  const int klo = wv * (D >> 2), khi = klo + (D >> 2);
  const float* g1p = g1T + (size_t)blockIdx.z * sG1;

  const float* wp[8];
  #pragma unroll
  for (int i = 0; i < 8; ++i) {
    int ff = f0 + (i >> 1);
    int fc = ff < F ? ff : 0;
    wp[i] = ((i & 1) ? C.Wys : C.Wyl) + (size_t)fc * D;
  }
  float acc[8];
  #pragma unroll
  for (int i = 0; i < 8; ++i) acc[i] = 0.f;
  #pragma unroll 4
  for (int k = klo; k < khi; k += 4) {
    const float a0 = g1p[(size_t)(k + 0) * B + b];
    const float a1 = g1p[(size_t)(k + 1) * B + b];
    const float a2 = g1p[(size_t)(k + 2) * B + b];
    const float a3 = g1p[(size_t)(k + 3) * B + b];
    #pragma unroll
    for (int i = 0; i < 8; ++i) {
      const float4 w4 = *(const float4*)(wp[i] + k);
      acc[i] = fmaf(w4.x, a0, fmaf(w4.y, a1, fmaf(w4.z, a2, fmaf(w4.w, a3, acc[i]))));
    }
  }

  #pragma unroll
  for (int i = 0; i < 8; ++i) sh[(wv * 8 + i) * 64 + lane] = acc[i];
  __syncthreads();

  int fi = tid >> 6, l = tid & 63;
  int ff = f0 + fi;
  int bb = b0 + l;
  float nl = 0.0f;
  if (ff < F) {
    float loc = sh[(0 * 8 + 2 * fi) * 64 + l] + sh[(1 * 8 + 2 * fi) * 64 + l]
              + sh[(2 * 8 + 2 * fi) * 64 + l] + sh[(3 * 8 + 2 * fi) * 64 + l] + C.byl[ff];
    float sp = sh[(0 * 8 + 2 * fi + 1) * 64 + l] + sh[(1 * 8 + 2 * fi + 1) * 64 + l]
             + sh[(2 * 8 + 2 * fi + 1) * 64 + l] + sh[(3 * 8 + 2 * fi + 1) * 64 + l] + C.bys[ff];
    float scale = softplusf_(sp) + 1e-6f;
    C.out[((size_t)bb * L + t) * F + ff] = loc;
    float xv = C.xT[((size_t)t * F + ff) * B + bb];
    float d = (xv - loc) / scale;
    nl = 0.5f * d * d + logf(scale) + 0.5f * LOG2PI_F;
  }
  waveReduceAtomicAdd(C.acc + 1, nl, tid);
}

// ---------------- step kernel (in-loop) ----------------
// pathA (768 blocks): phiGRU(i) | phiMLP1(i-1)+inline-z(i-2) | thGRU(i-3)
// pathB adds (1064): thMLP1(i-4)[768,1024) | yhead(i-5)[1024,1064)
__global__ __launch_bounds__(256) void k_step(
    CW C, int i,
    const float* xin, const float* phiPrev, float* phiCur,
    const float* h1prev, float* h1cur, float* zOut, const float* zIn,
    const float* thPrev, float* thCur, float* g1cur, const float* g1prev,
    const float* epsT) {
  __shared__ float sh[10240];  // 40 KB
  const int blk = blockIdx.x;

  if (blk < 256) {
    if (i < L)
      gru8<F>(blk, xin, phiPrev, C.phi_Wih, C.phi_Whh, C.phi_bih, C.phi_bhh,
              phiCur, 104, sh);
  } else if (blk < 512) {
    const bool doMain = (i >= 1 && i <= L);
    const bool doZ = (i >= 2 && i <= L + 1);
    const int blk2 = blk - 256;
    int rb, bg;
    rbbg_(blk2, rb, bg);
    if ((doMain || doZ) && (doMain || rb == 0))
      mlp1z(blk2, C, phiPrev, h1prev, epsT, h1cur, zOut, doMain, doZ, sh);
  } else if (blk < 768) {
    if (i >= 3 && i <= L + 2)
      gru8<Z>(blk - 512, zIn, thPrev, C.th_Wih, C.th_Whh, C.th_bih, C.th_bhh,
              thCur, 116, sh);
  } else if (blk < 1024) {
    if (i >= 4 && i <= L + 3 && g1cur != nullptr)
      lin8(blk - 768, thPrev, C.th_W1, C.th_b1, g1cur, sh);
  } else {
    if (i >= 5 && g1prev != nullptr)
      yhead8(blk - 1024, i - 5, C, g1prev, 0, sh);
  }
}

// ---------------- batched tail kernels (pathA; R1-proven pattern) ----------
__global__ __launch_bounds__(256) void k_lin_tail(
    const float* __restrict__ A1, long sA1,
    const float* __restrict__ W, const float* __restrict__ bias,
    float* __restrict__ outp, long sOut) {
  __shared__ float sh[2048];
  const float* A1p = A1 + (size_t)blockIdx.z * sA1;
  float* outpp = outp + (size_t)blockIdx.z * sOut;
  lin8((int)(blockIdx.x * 4 + blockIdx.y), A1p, W, bias, outpp, sh);
}

__global__ __launch_bounds__(256) void k_yhead_tail(
    CW C, const float* __restrict__ g1base, long sG1, int t_base) {
  __shared__ float sh[2048];
  yhead8((int)(blockIdx.x * 4 + blockIdx.y), t_base + blockIdx.z, C,
         g1base, sG1, sh);
}

}  // namespace

extern "C" void kernel_launch(void* const* d_in, const int* in_sizes, int n_in,
                              void* d_out, int out_size, void* d_ws, size_t ws_size,
                              hipStream_t stream) {
  const float* x        = (const float*)d_in[0];
  const float* phi_Wih  = (const float*)d_in[1];
  const float* phi_Whh  = (const float*)d_in[2];
  const float* phi_bih  = (const float*)d_in[3];
  const float* phi_bhh  = (const float*)d_in[4];
  const float* phi_W1   = (const float*)d_in[5];
  const float* phi_b1   = (const float*)d_in[6];
  const float* phi_W2   = (const float*)d_in[7];
  const float* phi_b2   = (const float*)d_in[8];
  const float* zloc_W   = (const float*)d_in[9];
  const float* zloc_b   = (const float*)d_in[10];
  const float* zscale_W = (const float*)d_in[11];
  const float* zscale_b = (const float*)d_in[12];
  const float* pu       = (const float*)d_in[13];
  const float* pw       = (const float*)d_in[14];
  const float* pb       = (const float*)d_in[15];
  const float* th_Wih   = (const float*)d_in[16];
  const float* th_Whh   = (const float*)d_in[17];
  const float* th_bih   = (const float*)d_in[18];
  const float* th_bhh   = (const float*)d_in[19];
  const float* th_W1    = (const float*)d_in[20];
  const float* th_b1    = (const float*)d_in[21];
  const float* th_W2    = (const float*)d_in[22];
  const float* th_b2    = (const float*)d_in[23];
  const float* xloc_W   = (const float*)d_in[24];
  const float* xloc_b   = (const float*)d_in[25];
  const float* xscale_W = (const float*)d_in[26];
  const float* xscale_b = (const float*)d_in[27];

  float* out = (float*)d_out;
  float* ws = (float*)d_ws;

  // workspace layout (floats)
  float* acc   = ws;                        // [0]=kld, [1]=recon
  float* eps_z = ws + 64;                   // LBZ
  float* xT    = eps_z + LBZ;               // LFB
  float* phi0  = xT + LFB;                  // HB  (phi_h ring)
  float* phi1  = phi0 + HB;                 // HB
  float* z0a   = phi1 + HB;                 // ZB  (post-flow z ring)
  float* z0b   = z0a + ZB;                  // ZB
  float* h1a   = z0b + ZB;                  // DB  (h1 ring)
  float* h1b   = h1a + DB;                  // DB
  float* Wzl   = h1b + DB;                  // Z*D
  float* Wzs   = Wzl + Z * D;               // Z*D
  float* bzl   = Wzs + Z * D;               // 64
  float* bzs   = bzl + 64;                  // 64
  float* Wyl   = bzs + 64;                  // F*D
  float* Wys   = Wyl + F * D;               // F*D
  float* byl   = Wys + F * D;               // 64
  float* bys   = byl + 64;                  // 64
  float* tailbase = bys + 64;

  // pathA: th_all (L+1 slots) + batched g1 chunk
  size_t floatsA = (size_t)(tailbase - ws) + (size_t)(L + 1) * HB + (size_t)TC * DB;
  const bool pathA = ws_size >= floatsA * sizeof(float);

  float* th_all = tailbase;                        // (L+1)*HB (pathA)
  float* g1_c   = th_all + (size_t)(L + 1) * HB;   // TC*DB (pathA)
  float* th0    = tailbase;                        // pathB th ring
  float* th1    = tailbase + HB;
  float* g1a    = tailbase + 2 * HB;               // pathB g1 ring
  float* g1b    = g1a + DB;

  hipMemsetAsync(acc, 0, 64 * sizeof(float), stream);
  hipMemsetAsync(phi1, 0, (size_t)HB * sizeof(float), stream);  // phi_h(-1)
  if (pathA) hipMemsetAsync(th_all, 0, (size_t)HB * sizeof(float), stream); // th_h(-1) in slot 0
  else       hipMemsetAsync(th1, 0, (size_t)HB * sizeof(float), stream);

  // JAX PRNG: key(42)=(0,42); split -> kz, kp
  uint32_t a0, a1, b0, b1;
  threefry2x32_(0u, 42u, 0u, 2u, a0, a1);
  threefry2x32_(0u, 42u, 1u, 3u, b0, b1);
  const uint32_t kz0 = a0, kz1 = b0, kp0 = a1, kp1 = b1;

  k_transpose_x<<<(B * L * F) / 256, 256, 0, stream>>>(x, xT);
  k_noise<<<HALF / 256, 256, 0, stream>>>(eps_z, acc, kz0, kz1, kp0, kp1);

  // Compose linear MLP2 into the z/y heads.
  k_compose<<<Z, 256, 0, stream>>>(zloc_W, zloc_b, phi_W2, phi_b2, Wzl, bzl);
  k_compose<<<Z, 256, 0, stream>>>(zscale_W, zscale_b, phi_W2, phi_b2, Wzs, bzs);
  k_compose<<<F, 256, 0, stream>>>(xloc_W, xloc_b, th_W2, th_b2, Wyl, byl);
  k_compose<<<F, 256, 0, stream>>>(xscale_W, xscale_b, th_W2, th_b2, Wys, bys);

  CW C;
  C.phi_Wih = phi_Wih; C.phi_Whh = phi_Whh; C.phi_bih = phi_bih; C.phi_bhh = phi_bhh;
  C.phi_W1 = phi_W1; C.phi_b1 = phi_b1;
  C.th_Wih = th_Wih; C.th_Whh = th_Whh; C.th_bih = th_bih; C.th_bhh = th_bhh;
  C.th_W1 = th_W1; C.th_b1 = th_b1;
  C.Wzl = Wzl; C.bzl = bzl; C.Wzs = Wzs; C.bzs = bzs;
  C.Wyl = Wyl; C.byl = byl; C.Wys = Wys; C.bys = bys;
  C.pu = pu; C.pw = pw; C.pb = pb; C.xT = xT;
  C.acc = acc; C.out = out;

  float* phiR[2] = {phi0, phi1};
  float* zR[2]   = {z0a, z0b};
  float* h1R[2]  = {h1a, h1b};
  float* thR[2]  = {th0, th1};
  float* g1R[2]  = {g1a, g1b};

  // In-loop: one launch per pipeline slot i.
  //   phiGRU(i) | phiMLP1(i-1)+inline-z(i-2) | thGRU(i-3) [pathB: +thMLP1(i-4)+yhead(i-5)]
  // Ring slots: phi write i&1 / read (i+1)&1; h1 write (i+1)&1 / read i&1;
  //             z write i&1 / read (i+1)&1. pathA th: slot s holds th_h(s-1);
  //             thGRU(i-3) reads slot i-3 (= th_h(i-4)), writes slot i-2.
  const int iMax = pathA ? (L + 2) : (L + 4);
  const int grid = pathA ? 768 : 1064;
  for (int i = 0; i <= iMax; ++i) {
    const float* xin     = xT + (size_t)((i < L) ? i : 0) * F * B;
    const float* phiPrev = phiR[(i + 1) & 1];
    float*       phiCur  = phiR[i & 1];
    const float* h1prev  = h1R[i & 1];
    float*       h1cur   = h1R[(i + 1) & 1];
    float*       zOut    = zR[i & 1];
    const float* zIn     = zR[(i + 1) & 1];
    const float* epsT    = eps_z +
        (size_t)((i >= 2 && i <= L + 1) ? (i - 2) : 0) * B * Z;

    const float* thPrev;
    float*       thCur;
    float*       g1cur = nullptr;
    const float* g1prev = nullptr;
    if (pathA) {
      const int s = (i >= 3) ? (i - 3) : 0;
      thPrev = th_all + (size_t)s * HB;        // th_h(i-4)
      thCur  = th_all + (size_t)(s + 1) * HB;  // th_h(i-3)
    } else {
      thPrev = thR[i & 1];          // th_h(i-4)
      thCur  = thR[(i + 1) & 1];    // th_h(i-3)
      g1cur  = g1R[i & 1];          // g1(i-4)
      g1prev = g1R[(i + 1) & 1];    // g1(i-5)
    }

    k_step<<<grid, 256, 0, stream>>>(C, i, xin, phiPrev, phiCur, h1prev, h1cur,
                                     zOut, zIn, thPrev, thCur, g1cur, g1prev,
                                     epsT);
  }

  if (pathA) {
    // Batched theta tail: g1(t) = relu(thW1 @ th_h(t)); yhead over t-chunks.
    // th_h(t) lives in th_all slot t+1.
    for (int c = 0; c < L / TC; ++c) {
      const float* thh = th_all + (size_t)(c * TC + 1) * HB;
      dim3 g1(D / 8, B / 64, TC);
      k_lin_tail<<<g1, 256, 0, stream>>>(thh, HB, th_W1, th_b1, g1_c, DB);
      dim3 gy((F + 3) / 4, B / 64, TC);
      k_yhead_tail<<<gy, 256, 0, stream>>>(C, g1_c, DB, c * TC);
    }
  }

  k_finalize<<<1, 1, 0, stream>>>(acc, out);
}